// Round 6
// baseline (470.368 us; speedup 1.0000x reference)
//
#include <hip/hip_runtime.h>
#include <hip/hip_cooperative_groups.h>
#include <math.h>

namespace cg = cooperative_groups;

#define N 4096
#define C 512
#define EMB 38
#define HEADS 4
#define HID 64
#define F1 256       // HEADS*HID
#define MAXN 128     // max neighbors (p=0.01 -> mean 41, >13 sigma headroom)
#define RPB 8        // rows per block (coop path)
#define BLKS 512     // 2 blocks/CU on 256 CUs -> co-resident guaranteed

__device__ __forceinline__ float wr_sum(float v) {
#pragma unroll
    for (int o = 32; o > 0; o >>= 1) v += __shfl_xor(v, o);
    return v;
}
__device__ __forceinline__ float wr_max(float v) {
#pragma unroll
    for (int o = 32; o > 0; o >>= 1) v = fmaxf(v, __shfl_xor(v, o));
    return v;
}

// ---------------- shared-memory union for the fused kernel ----------------
struct SmemAgg {
    int nbrs[MAXN];
    float wts[HEADS][MAXN + 1];
    float lsum[HEADS];
    float sacc[4][F1];
    float red[HEADS];
};
struct SmemG1 {
    float fs[RPB][8];
    float xs[RPB][40];   // EMB=38 padded to 40
};
struct SmemG2 {
    float4 xs4[RPB][F1 / 4];
};
struct SmemPool {
    float sacc[4][HID];
    float ce[HID];
};
union Smem {
    SmemAgg a;
    SmemG1 g1;
    SmemG2 g2;
    SmemPool p;
};

// ================= single fused cooperative kernel =================
__global__ __launch_bounds__(256, 2) void k_all(
        const float* __restrict__ adj, const float* __restrict__ nf, const float* __restrict__ pm,
        const float* __restrict__ W1, const float* __restrict__ as1, const float* __restrict__ ad1,
        const float* __restrict__ g1, const float* __restrict__ b1,
        const float* __restrict__ W2, const float* __restrict__ as2, const float* __restrict__ ad2,
        const float* __restrict__ g2, const float* __restrict__ b2,
        const float* __restrict__ Wsc, const float* __restrict__ bsc,
        const float* __restrict__ Wo, const float* __restrict__ bo,
        float* __restrict__ out, float* __restrict__ ws) {
    cg::grid_group gg = cg::this_grid();
    __shared__ Smem sm;
    int tid = threadIdx.x, blk = blockIdx.x;
    int wv = tid >> 6, lane = tid & 63;

    float* h1 = ws;
    float* s1 = h1 + (size_t)N * F1;
    float* d1 = s1 + N * HEADS;
    float* x1 = d1 + N * HEADS;
    float* h2 = x1 + (size_t)N * F1;
    float* s2 = h2 + (size_t)N * F1;
    float* d2 = s2 + N * HEADS;
    float* x2 = d2 + N * HEADS;
    int* cnt  = (int*)(x2 + N * HID);
    int* idx  = cnt + N;

    // ===== stage A: CSR build — wave per row, ballot compaction =====
#pragma unroll
    for (int rep = 0; rep < 2; ++rep) {
        int i = blk * RPB + rep * 4 + wv;
        const float4* row = (const float4*)(adj + (size_t)i * N);
        unsigned long long below = (lane == 63) ? (~0ull >> 1) : ((1ull << lane) - 1);
        int base = 0;
        int* orow = idx + i * MAXN;
        for (int it = 0; it < 16; ++it) {
            float4 a = row[it * 64 + lane];
            int col0 = 4 * (it * 64 + lane);
            float vals[4] = {a.x, a.y, a.z, a.w};
#pragma unroll
            for (int comp = 0; comp < 4; ++comp) {
                unsigned long long m = __ballot(vals[comp] > 0.f);
                if (vals[comp] > 0.f) {
                    int p = base + __popcll(m & below);
                    if (p < MAXN) orow[p] = col0 + comp;
                }
                base += __popcll(m);
            }
        }
        if (lane == 0) cnt[i] = min(base, MAXN);
    }

    // ===== stage B: embed + gemm1 (8 rows) + attention dots =====
    {
        int n0 = blk * RPB;
        if (tid < RPB * 8) sm.g1.fs[tid >> 3][tid & 7] = nf[(size_t)n0 * 8 + tid];
        if (tid < RPB * 2) sm.g1.xs[tid >> 1][38 + (tid & 1)] = 0.f;
        __syncthreads();
        {
            int r = tid & 7;
            int t = tid >> 3;               // 0..31
            const float* f = sm.g1.fs[r];
            for (int pass = 0; pass < 2; ++pass, t += 32) {
                if (t >= EMB) break;
                float val;
                if (t < 6) { int nt = min(max((int)f[0], 0), 5); val = (t == nt) ? 1.f : 0.f; }
                else if (t == 6) val = log1pf(f[1]);
                else if (t < 31) {
                    int q = (t - 7) & 7, s = (t - 7) >> 3, m = q >> 1;
                    float base = (s == 0) ? f[2] : (s == 1) ? f[3] : f[4] * 100.f;
                    float div = expf((2.f * m) * (-logf(10000.f) / 8.f));
                    float sc = base * div;
                    val = (q & 1) ? cosf(sc) : sinf(sc);
                }
                else if (t < 36) { int role = min(max((int)f[5], 0), 4); val = (t - 31 == role) ? 1.f : 0.f; }
                else val = (t == 36) ? f[6] : f[7];
                sm.g1.xs[r][t] = val;
            }
        }
        __syncthreads();
        float acc[RPB];
#pragma unroll
        for (int r = 0; r < RPB; ++r) acc[r] = 0.f;
#pragma unroll
        for (int kk = 0; kk < 9; ++kk) {
            float w0 = W1[(4 * kk + 0) * F1 + tid];
            float w1 = W1[(4 * kk + 1) * F1 + tid];
            float w2 = W1[(4 * kk + 2) * F1 + tid];
            float w3 = W1[(4 * kk + 3) * F1 + tid];
#pragma unroll
            for (int r = 0; r < RPB; ++r) {
                float4 x = *(const float4*)&sm.g1.xs[r][4 * kk];
                acc[r] = fmaf(x.x, w0, fmaf(x.y, w1, fmaf(x.z, w2, fmaf(x.w, w3, acc[r]))));
            }
        }
#pragma unroll
        for (int k = 36; k < EMB; ++k) {
            float wvv = W1[k * F1 + tid];
#pragma unroll
            for (int r = 0; r < RPB; ++r) acc[r] = fmaf(sm.g1.xs[r][k], wvv, acc[r]);
        }
        float av = as1[tid], dvv = ad1[tid];
#pragma unroll
        for (int r = 0; r < RPB; ++r) {
            h1[(size_t)(n0 + r) * F1 + tid] = acc[r];
            float ssum = wr_sum(acc[r] * av);
            float dsum = wr_sum(acc[r] * dvv);
            if (lane == 0) { s1[(n0 + r) * HEADS + wv] = ssum; d1[(n0 + r) * HEADS + wv] = dsum; }
        }
    }
    gg.sync();

    // ===== stage C: agg1 (concat) + LN(256) + ELU — 8 rows sequential =====
    for (int rr = 0; rr < RPB; ++rr) {
        int i = blk * RPB + rr;
        __syncthreads();
        int c = cnt[i];
        if (tid < c) sm.a.nbrs[tid] = idx[i * MAXN + tid];
        __syncthreads();
        if (tid < c) {
            float4 dd = ((const float4*)d1)[sm.a.nbrs[tid]];
            float4 ss = ((const float4*)s1)[i];
            float e0 = ss.x + dd.x, e1 = ss.y + dd.y, e2 = ss.z + dd.z, e3 = ss.w + dd.w;
            sm.a.wts[0][tid] = e0 > 0.f ? e0 : 0.2f * e0;
            sm.a.wts[1][tid] = e1 > 0.f ? e1 : 0.2f * e1;
            sm.a.wts[2][tid] = e2 > 0.f ? e2 : 0.2f * e2;
            sm.a.wts[3][tid] = e3 > 0.f ? e3 : 0.2f * e3;
        }
        __syncthreads();
        {
            float m = -INFINITY;
            for (int jj = lane; jj < c; jj += 64) m = fmaxf(m, sm.a.wts[wv][jj]);
            m = wr_max(m);
            float l = 0.f;
            for (int jj = lane; jj < c; jj += 64) { float t = expf(sm.a.wts[wv][jj] - m); sm.a.wts[wv][jj] = t; l += t; }
            l = wr_sum(l);
            if (lane == 0) sm.a.lsum[wv] = l;
        }
        __syncthreads();
        int hq = lane >> 4;
        const float4* hv = (const float4*)h1;
        float4 acc = {0.f, 0.f, 0.f, 0.f};
        int jj = wv;
        for (; jj + 4 < c; jj += 8) {
            int na = sm.a.nbrs[jj], nb = sm.a.nbrs[jj + 4];
            float wa = sm.a.wts[hq][jj], wb = sm.a.wts[hq][jj + 4];
            float4 va = hv[(size_t)na * 64 + lane];
            float4 vb = hv[(size_t)nb * 64 + lane];
            acc.x = fmaf(wa, va.x, acc.x); acc.y = fmaf(wa, va.y, acc.y);
            acc.z = fmaf(wa, va.z, acc.z); acc.w = fmaf(wa, va.w, acc.w);
            acc.x = fmaf(wb, vb.x, acc.x); acc.y = fmaf(wb, vb.y, acc.y);
            acc.z = fmaf(wb, vb.z, acc.z); acc.w = fmaf(wb, vb.w, acc.w);
        }
        for (; jj < c; jj += 4) {
            int na = sm.a.nbrs[jj];
            float wa = sm.a.wts[hq][jj];
            float4 va = hv[(size_t)na * 64 + lane];
            acc.x = fmaf(wa, va.x, acc.x); acc.y = fmaf(wa, va.y, acc.y);
            acc.z = fmaf(wa, va.z, acc.z); acc.w = fmaf(wa, va.w, acc.w);
        }
        ((float4*)&sm.a.sacc[wv][0])[lane] = acc;
        __syncthreads();
        float tot = (sm.a.sacc[0][tid] + sm.a.sacc[1][tid] + sm.a.sacc[2][tid] + sm.a.sacc[3][tid]) / sm.a.lsum[wv];
        float s = wr_sum(tot);
        if (lane == 0) sm.a.red[wv] = s;
        __syncthreads();
        float mu = (sm.a.red[0] + sm.a.red[1] + sm.a.red[2] + sm.a.red[3]) * (1.f / F1);
        float dvv = tot - mu;
        float s2v = wr_sum(dvv * dvv);
        __syncthreads();
        if (lane == 0) sm.a.red[wv] = s2v;
        __syncthreads();
        float var = (sm.a.red[0] + sm.a.red[1] + sm.a.red[2] + sm.a.red[3]) * (1.f / F1);
        float y = dvv * rsqrtf(var + 1e-5f) * g1[tid] + b1[tid];
        x1[(size_t)i * F1 + tid] = y > 0.f ? y : expm1f(y);
    }

    // ===== stage D: gemm2 — own rows only, no grid sync needed =====
    {
        __syncthreads();
        int n0 = blk * RPB;
        {
            int r = tid >> 5, kk = tid & 31;
            const float4* x1v = (const float4*)x1;
            sm.g2.xs4[r][kk]      = x1v[(size_t)(n0 + r) * 64 + kk];
            sm.g2.xs4[r][kk + 32] = x1v[(size_t)(n0 + r) * 64 + kk + 32];
        }
        __syncthreads();
        float acc[RPB];
#pragma unroll
        for (int r = 0; r < RPB; ++r) acc[r] = 0.f;
        for (int kk = 0; kk < F1 / 4; ++kk) {
            float w0 = W2[(4 * kk + 0) * F1 + tid];
            float w1 = W2[(4 * kk + 1) * F1 + tid];
            float w2 = W2[(4 * kk + 2) * F1 + tid];
            float w3 = W2[(4 * kk + 3) * F1 + tid];
#pragma unroll
            for (int r = 0; r < RPB; ++r) {
                float4 x = sm.g2.xs4[r][kk];
                acc[r] = fmaf(x.x, w0, fmaf(x.y, w1, fmaf(x.z, w2, fmaf(x.w, w3, acc[r]))));
            }
        }
        float av = as2[tid], dvv = ad2[tid];
#pragma unroll
        for (int r = 0; r < RPB; ++r) {
            h2[(size_t)(n0 + r) * F1 + tid] = acc[r];
            float ssum = wr_sum(acc[r] * av);
            float dsum = wr_sum(acc[r] * dvv);
            if (lane == 0) { s2[(n0 + r) * HEADS + wv] = ssum; d2[(n0 + r) * HEADS + wv] = dsum; }
        }
    }
    gg.sync();

    // ===== stage E: agg2 (mean heads) + LN(64) + ELU — 8 rows sequential =====
    for (int rr = 0; rr < RPB; ++rr) {
        int i = blk * RPB + rr;
        __syncthreads();
        int c = cnt[i];
        if (tid < c) sm.a.nbrs[tid] = idx[i * MAXN + tid];
        __syncthreads();
        if (tid < c) {
            float4 dd = ((const float4*)d2)[sm.a.nbrs[tid]];
            float4 ss = ((const float4*)s2)[i];
            float e0 = ss.x + dd.x, e1 = ss.y + dd.y, e2 = ss.z + dd.z, e3 = ss.w + dd.w;
            sm.a.wts[0][tid] = e0 > 0.f ? e0 : 0.2f * e0;
            sm.a.wts[1][tid] = e1 > 0.f ? e1 : 0.2f * e1;
            sm.a.wts[2][tid] = e2 > 0.f ? e2 : 0.2f * e2;
            sm.a.wts[3][tid] = e3 > 0.f ? e3 : 0.2f * e3;
        }
        __syncthreads();
        {
            float m = -INFINITY;
            for (int jj = lane; jj < c; jj += 64) m = fmaxf(m, sm.a.wts[wv][jj]);
            m = wr_max(m);
            float l = 0.f;
            for (int jj = lane; jj < c; jj += 64) { float t = expf(sm.a.wts[wv][jj] - m); sm.a.wts[wv][jj] = t; l += t; }
            l = wr_sum(l);
            if (lane == 0) sm.a.lsum[wv] = l;
        }
        __syncthreads();
        int hq = lane >> 4;
        const float4* hvv = (const float4*)h2;
        float4 acc = {0.f, 0.f, 0.f, 0.f};
        int jj = wv;
        for (; jj + 4 < c; jj += 8) {
            int na = sm.a.nbrs[jj], nb = sm.a.nbrs[jj + 4];
            float wa = sm.a.wts[hq][jj], wb = sm.a.wts[hq][jj + 4];
            float4 va = hvv[(size_t)na * 64 + lane];
            float4 vb = hvv[(size_t)nb * 64 + lane];
            acc.x = fmaf(wa, va.x, acc.x); acc.y = fmaf(wa, va.y, acc.y);
            acc.z = fmaf(wa, va.z, acc.z); acc.w = fmaf(wa, va.w, acc.w);
            acc.x = fmaf(wb, vb.x, acc.x); acc.y = fmaf(wb, vb.y, acc.y);
            acc.z = fmaf(wb, vb.z, acc.z); acc.w = fmaf(wb, vb.w, acc.w);
        }
        for (; jj < c; jj += 4) {
            int na = sm.a.nbrs[jj];
            float wa = sm.a.wts[hq][jj];
            float4 va = hvv[(size_t)na * 64 + lane];
            acc.x = fmaf(wa, va.x, acc.x); acc.y = fmaf(wa, va.y, acc.y);
            acc.z = fmaf(wa, va.z, acc.z); acc.w = fmaf(wa, va.w, acc.w);
        }
        ((float4*)&sm.a.sacc[wv][0])[lane] = acc;
        __syncthreads();
        if (wv == 0) {
            float t0 = 0.f, t1 = 0.f, t2 = 0.f, t3 = 0.f;
#pragma unroll
            for (int w = 0; w < 4; ++w) {
                t0 += sm.a.sacc[w][lane];
                t1 += sm.a.sacc[w][lane + 64];
                t2 += sm.a.sacc[w][lane + 128];
                t3 += sm.a.sacc[w][lane + 192];
            }
            float mv = (t0 / sm.a.lsum[0] + t1 / sm.a.lsum[1] + t2 / sm.a.lsum[2] + t3 / sm.a.lsum[3]) * 0.25f;
            float mu = wr_sum(mv) * (1.f / HID);
            float dvv = mv - mu;
            float var = wr_sum(dvv * dvv) * (1.f / HID);
            float y = dvv * rsqrtf(var + 1e-5f) * g2[lane] + b2[lane];
            x2[i * HID + lane] = y > 0.f ? y : expm1f(y);
        }
        __syncthreads();
    }
    gg.sync();

    // ===== stage F: clause pooling + scorer — exactly 1 clause per block =====
    {
        int cc = blk;
        float acc = 0.f;
        const float4* pmv = (const float4*)(pm + (size_t)cc * N);
#pragma unroll
        for (int it = 0; it < 4; ++it) {
            int vi = wv * 256 + it * 64 + lane;
            float4 p4 = pmv[vi];
            float pc[4] = {p4.x, p4.y, p4.z, p4.w};
#pragma unroll
            for (int comp = 0; comp < 4; ++comp) {
                unsigned long long msk = __ballot(pc[comp] != 0.f);
                while (msk) {
                    int bpos = __ffsll(msk) - 1;
                    msk &= msk - 1;
                    float pj = __shfl(pc[comp], bpos);
                    int j = (wv * 256 + it * 64 + bpos) * 4 + comp;
                    acc += pj * x2[(size_t)j * HID + lane];
                }
            }
        }
        sm.p.sacc[wv][lane] = acc;
        __syncthreads();
        if (wv == 0) sm.p.ce[lane] = sm.p.sacc[0][lane] + sm.p.sacc[1][lane] + sm.p.sacc[2][lane] + sm.p.sacc[3][lane];
        __syncthreads();
        if (wv == 0) {
            float hd = bsc[lane];
#pragma unroll 8
            for (int k = 0; k < HID; ++k) hd = fmaf(sm.p.ce[k], Wsc[k * HID + lane], hd);
            hd = fmaxf(hd, 0.f);
            float v = wr_sum(hd * Wo[lane]);
            if (lane == 0) out[cc] = v + bo[0];
        }
    }
}

// ================= fallback path: the round-4 (passing) 6-kernel pipeline =================
__global__ __launch_bounds__(256) void f_build(const float* __restrict__ adj,
                                               int* __restrict__ cnt, int* __restrict__ idx) {
    int wv = threadIdx.x >> 6, lane = threadIdx.x & 63;
    int i = blockIdx.x * 4 + wv;
    const float4* row = (const float4*)(adj + (size_t)i * N);
    unsigned long long below = (lane == 63) ? ~0ull >> 1 : (1ull << lane) - 1;
    int base = 0;
    int* orow = idx + i * MAXN;
#pragma unroll 2
    for (int it = 0; it < 16; ++it) {
        float4 a = row[it * 64 + lane];
        int col0 = 4 * (it * 64 + lane);
        float vals[4] = {a.x, a.y, a.z, a.w};
#pragma unroll
        for (int comp = 0; comp < 4; ++comp) {
            unsigned long long m = __ballot(vals[comp] > 0.f);
            if (vals[comp] > 0.f) {
                int p = base + __popcll(m & below);
                if (p < MAXN) orow[p] = col0 + comp;
            }
            base += __popcll(m);
        }
    }
    if (lane == 0) cnt[i] = min(base, MAXN);
}

__global__ __launch_bounds__(256) void f_gemm1(const float* __restrict__ nf, const float* __restrict__ W1,
                                               const float* __restrict__ asrc, const float* __restrict__ adst,
                                               float* __restrict__ h1, float* __restrict__ s1, float* __restrict__ d1) {
    int n0 = blockIdx.x * RPB, tid = threadIdx.x;
    __shared__ float fs[RPB][8];
    __shared__ float xs[RPB][40];
    if (tid < RPB * 8) fs[tid >> 3][tid & 7] = nf[(size_t)n0 * 8 + tid];
    if (tid < RPB * 2) xs[tid >> 1][38 + (tid & 1)] = 0.f;
    __syncthreads();
    {
        int r = tid & 7;
        int t = tid >> 3;
        const float* f = fs[r];
        for (int pass = 0; pass < 2; ++pass, t += 32) {
            if (t >= EMB) break;
            float val;
            if (t < 6) { int nt = min(max((int)f[0], 0), 5); val = (t == nt) ? 1.f : 0.f; }
            else if (t == 6) val = log1pf(f[1]);
            else if (t < 31) {
                int q = (t - 7) & 7, s = (t - 7) >> 3, m = q >> 1;
                float base = (s == 0) ? f[2] : (s == 1) ? f[3] : f[4] * 100.f;
                float div = expf((2.f * m) * (-logf(10000.f) / 8.f));
                float sc = base * div;
                val = (q & 1) ? cosf(sc) : sinf(sc);
            }
            else if (t < 36) { int role = min(max((int)f[5], 0), 4); val = (t - 31 == role) ? 1.f : 0.f; }
            else val = (t == 36) ? f[6] : f[7];
            xs[r][t] = val;
        }
    }
    __syncthreads();
    float acc[RPB];
#pragma unroll
    for (int r = 0; r < RPB; ++r) acc[r] = 0.f;
#pragma unroll
    for (int kk = 0; kk < 9; ++kk) {
        float w0 = W1[(4 * kk + 0) * F1 + tid];
        float w1 = W1[(4 * kk + 1) * F1 + tid];
        float w2 = W1[(4 * kk + 2) * F1 + tid];
        float w3 = W1[(4 * kk + 3) * F1 + tid];
#pragma unroll
        for (int r = 0; r < RPB; ++r) {
            float4 x = *(const float4*)&xs[r][4 * kk];
            acc[r] = fmaf(x.x, w0, fmaf(x.y, w1, fmaf(x.z, w2, fmaf(x.w, w3, acc[r]))));
        }
    }
#pragma unroll
    for (int k = 36; k < EMB; ++k) {
        float wvv = W1[k * F1 + tid];
#pragma unroll
        for (int r = 0; r < RPB; ++r) acc[r] = fmaf(xs[r][k], wvv, acc[r]);
    }
    int h = tid >> 6, lane = tid & 63;
    float av = asrc[tid], dv = adst[tid];
#pragma unroll
    for (int r = 0; r < RPB; ++r) {
        h1[(size_t)(n0 + r) * F1 + tid] = acc[r];
        float ss = wr_sum(acc[r] * av);
        float dd = wr_sum(acc[r] * dv);
        if (lane == 0) { s1[(n0 + r) * HEADS + h] = ss; d1[(n0 + r) * HEADS + h] = dd; }
    }
}

__global__ __launch_bounds__(256) void f_gemm2(const float* __restrict__ x1, const float* __restrict__ W2,
                                               const float* __restrict__ asrc, const float* __restrict__ adst,
                                               float* __restrict__ h2, float* __restrict__ s2, float* __restrict__ d2) {
    int n0 = blockIdx.x * RPB, tid = threadIdx.x;
    __shared__ float4 xs4[RPB][F1 / 4];
    {
        int r = tid >> 5, kk = tid & 31;
        const float4* x1v = (const float4*)x1;
        xs4[r][kk]      = x1v[(size_t)(n0 + r) * 64 + kk];
        xs4[r][kk + 32] = x1v[(size_t)(n0 + r) * 64 + kk + 32];
    }
    __syncthreads();
    float acc[RPB];
#pragma unroll
    for (int r = 0; r < RPB; ++r) acc[r] = 0.f;
    for (int kk = 0; kk < F1 / 4; ++kk) {
        float w0 = W2[(4 * kk + 0) * F1 + tid];
        float w1 = W2[(4 * kk + 1) * F1 + tid];
        float w2 = W2[(4 * kk + 2) * F1 + tid];
        float w3 = W2[(4 * kk + 3) * F1 + tid];
#pragma unroll
        for (int r = 0; r < RPB; ++r) {
            float4 x = xs4[r][kk];
            acc[r] = fmaf(x.x, w0, fmaf(x.y, w1, fmaf(x.z, w2, fmaf(x.w, w3, acc[r]))));
        }
    }
    int h = tid >> 6, lane = tid & 63;
    float av = asrc[tid], dv = adst[tid];
#pragma unroll
    for (int r = 0; r < RPB; ++r) {
        h2[(size_t)(n0 + r) * F1 + tid] = acc[r];
        float ss = wr_sum(acc[r] * av);
        float dd = wr_sum(acc[r] * dv);
        if (lane == 0) { s2[(n0 + r) * HEADS + h] = ss; d2[(n0 + r) * HEADS + h] = dd; }
    }
}

__global__ __launch_bounds__(256) void f_agg1(const float* __restrict__ h1, const float* __restrict__ s1,
                                              const float* __restrict__ d1, const int* __restrict__ cnt,
                                              const int* __restrict__ idx, const float* __restrict__ g,
                                              const float* __restrict__ b, float* __restrict__ xo) {
    int i = blockIdx.x, tid = threadIdx.x;
    int wv = tid >> 6, lane = tid & 63;
    __shared__ int nbrs[MAXN];
    __shared__ float wts[HEADS][MAXN + 1];
    __shared__ float lsum[HEADS];
    __shared__ float sacc[4][F1];
    __shared__ float red[HEADS];
    int c = cnt[i];
    if (tid < c) nbrs[tid] = idx[i * MAXN + tid];
    __syncthreads();
    if (tid < c) {
        float4 dd = ((const float4*)d1)[nbrs[tid]];
        float4 ss = ((const float4*)s1)[i];
        float e0 = ss.x + dd.x, e1 = ss.y + dd.y, e2 = ss.z + dd.z, e3 = ss.w + dd.w;
        wts[0][tid] = e0 > 0.f ? e0 : 0.2f * e0;
        wts[1][tid] = e1 > 0.f ? e1 : 0.2f * e1;
        wts[2][tid] = e2 > 0.f ? e2 : 0.2f * e2;
        wts[3][tid] = e3 > 0.f ? e3 : 0.2f * e3;
    }
    __syncthreads();
    {
        float m = -INFINITY;
        for (int jj = lane; jj < c; jj += 64) m = fmaxf(m, wts[wv][jj]);
        m = wr_max(m);
        float l = 0.f;
        for (int jj = lane; jj < c; jj += 64) { float t = expf(wts[wv][jj] - m); wts[wv][jj] = t; l += t; }
        l = wr_sum(l);
        if (lane == 0) lsum[wv] = l;
    }
    __syncthreads();
    int hq = lane >> 4;
    const float4* hv = (const float4*)h1;
    float4 acc = {0.f, 0.f, 0.f, 0.f};
    int jj = wv;
    for (; jj + 4 < c; jj += 8) {
        int na = nbrs[jj], nb = nbrs[jj + 4];
        float wa = wts[hq][jj], wb = wts[hq][jj + 4];
        float4 va = hv[(size_t)na * 64 + lane];
        float4 vb = hv[(size_t)nb * 64 + lane];
        acc.x = fmaf(wa, va.x, acc.x); acc.y = fmaf(wa, va.y, acc.y);
        acc.z = fmaf(wa, va.z, acc.z); acc.w = fmaf(wa, va.w, acc.w);
        acc.x = fmaf(wb, vb.x, acc.x); acc.y = fmaf(wb, vb.y, acc.y);
        acc.z = fmaf(wb, vb.z, acc.z); acc.w = fmaf(wb, vb.w, acc.w);
    }
    for (; jj < c; jj += 4) {
        int na = nbrs[jj];
        float wa = wts[hq][jj];
        float4 va = hv[(size_t)na * 64 + lane];
        acc.x = fmaf(wa, va.x, acc.x); acc.y = fmaf(wa, va.y, acc.y);
        acc.z = fmaf(wa, va.z, acc.z); acc.w = fmaf(wa, va.w, acc.w);
    }
    ((float4*)&sacc[wv][0])[lane] = acc;
    __syncthreads();
    float tot = (sacc[0][tid] + sacc[1][tid] + sacc[2][tid] + sacc[3][tid]) / lsum[wv];
    float s = wr_sum(tot);
    if (lane == 0) red[wv] = s;
    __syncthreads();
    float mu = (red[0] + red[1] + red[2] + red[3]) * (1.f / F1);
    float dvv = tot - mu;
    float s2 = wr_sum(dvv * dvv);
    __syncthreads();
    if (lane == 0) red[wv] = s2;
    __syncthreads();
    float var = (red[0] + red[1] + red[2] + red[3]) * (1.f / F1);
    float y = dvv * rsqrtf(var + 1e-5f) * g[tid] + b[tid];
    xo[(size_t)i * F1 + tid] = y > 0.f ? y : expm1f(y);
}

__global__ __launch_bounds__(256) void f_agg2(const float* __restrict__ h2, const float* __restrict__ s2,
                                              const float* __restrict__ d2, const int* __restrict__ cnt,
                                              const int* __restrict__ idx, const float* __restrict__ g,
                                              const float* __restrict__ b, float* __restrict__ xo) {
    int i = blockIdx.x, tid = threadIdx.x;
    int wv = tid >> 6, lane = tid & 63;
    __shared__ int nbrs[MAXN];
    __shared__ float wts[HEADS][MAXN + 1];
    __shared__ float lsum[HEADS];
    __shared__ float sacc[4][F1];
    int c = cnt[i];
    if (tid < c) nbrs[tid] = idx[i * MAXN + tid];
    __syncthreads();
    if (tid < c) {
        float4 dd = ((const float4*)d2)[nbrs[tid]];
        float4 ss = ((const float4*)s2)[i];
        float e0 = ss.x + dd.x, e1 = ss.y + dd.y, e2 = ss.z + dd.z, e3 = ss.w + dd.w;
        wts[0][tid] = e0 > 0.f ? e0 : 0.2f * e0;
        wts[1][tid] = e1 > 0.f ? e1 : 0.2f * e1;
        wts[2][tid] = e2 > 0.f ? e2 : 0.2f * e2;
        wts[3][tid] = e3 > 0.f ? e3 : 0.2f * e3;
    }
    __syncthreads();
    {
        float m = -INFINITY;
        for (int jj = lane; jj < c; jj += 64) m = fmaxf(m, wts[wv][jj]);
        m = wr_max(m);
        float l = 0.f;
        for (int jj = lane; jj < c; jj += 64) { float t = expf(wts[wv][jj] - m); wts[wv][jj] = t; l += t; }
        l = wr_sum(l);
        if (lane == 0) lsum[wv] = l;
    }
    __syncthreads();
    int hq = lane >> 4;
    const float4* hvv = (const float4*)h2;
    float4 acc = {0.f, 0.f, 0.f, 0.f};
    int jj = wv;
    for (; jj + 4 < c; jj += 8) {
        int na = nbrs[jj], nb = nbrs[jj + 4];
        float wa = wts[hq][jj], wb = wts[hq][jj + 4];
        float4 va = hvv[(size_t)na * 64 + lane];
        float4 vb = hvv[(size_t)nb * 64 + lane];
        acc.x = fmaf(wa, va.x, acc.x); acc.y = fmaf(wa, va.y, acc.y);
        acc.z = fmaf(wa, va.z, acc.z); acc.w = fmaf(wa, va.w, acc.w);
        acc.x = fmaf(wb, vb.x, acc.x); acc.y = fmaf(wb, vb.y, acc.y);
        acc.z = fmaf(wb, vb.z, acc.z); acc.w = fmaf(wb, vb.w, acc.w);
    }
    for (; jj < c; jj += 4) {
        int na = nbrs[jj];
        float wa = wts[hq][jj];
        float4 va = hvv[(size_t)na * 64 + lane];
        acc.x = fmaf(wa, va.x, acc.x); acc.y = fmaf(wa, va.y, acc.y);
        acc.z = fmaf(wa, va.z, acc.z); acc.w = fmaf(wa, va.w, acc.w);
    }
    ((float4*)&sacc[wv][0])[lane] = acc;
    __syncthreads();
    if (wv == 0) {
        float t0 = 0.f, t1 = 0.f, t2 = 0.f, t3 = 0.f;
#pragma unroll
        for (int w = 0; w < 4; ++w) {
            t0 += sacc[w][lane];
            t1 += sacc[w][lane + 64];
            t2 += sacc[w][lane + 128];
            t3 += sacc[w][lane + 192];
        }
        float mv = (t0 / lsum[0] + t1 / lsum[1] + t2 / lsum[2] + t3 / lsum[3]) * 0.25f;
        float mu = wr_sum(mv) * (1.f / HID);
        float dvv = mv - mu;
        float var = wr_sum(dvv * dvv) * (1.f / HID);
        float y = dvv * rsqrtf(var + 1e-5f) * g[lane] + b[lane];
        xo[i * HID + lane] = y > 0.f ? y : expm1f(y);
    }
}

__global__ __launch_bounds__(256) void f_poolscore(const float* __restrict__ pm, const float* __restrict__ x2,
                                                   const float* __restrict__ Ws, const float* __restrict__ bs,
                                                   const float* __restrict__ Wo, const float* __restrict__ bo,
                                                   float* __restrict__ out) {
    int c = blockIdx.x, tid = threadIdx.x;
    int w = tid >> 6, lane = tid & 63;
    __shared__ float sacc[4][HID];
    __shared__ float ce_s[HID];
    float acc = 0.f;
    const float4* pmv = (const float4*)(pm + (size_t)c * N);
#pragma unroll
    for (int it = 0; it < 4; ++it) {
        int vi = w * 256 + it * 64 + lane;
        float4 p4 = pmv[vi];
        float pc[4] = {p4.x, p4.y, p4.z, p4.w};
#pragma unroll
        for (int comp = 0; comp < 4; ++comp) {
            unsigned long long msk = __ballot(pc[comp] != 0.f);
            while (msk) {
                int bpos = __ffsll(msk) - 1;
                msk &= msk - 1;
                float pj = __shfl(pc[comp], bpos);
                int j = (w * 256 + it * 64 + bpos) * 4 + comp;
                acc += pj * x2[(size_t)j * HID + lane];
            }
        }
    }
    sacc[w][lane] = acc;
    __syncthreads();
    if (w == 0) ce_s[lane] = sacc[0][lane] + sacc[1][lane] + sacc[2][lane] + sacc[3][lane];
    __syncthreads();
    if (w == 0) {
        float hd = bs[lane];
#pragma unroll 8
        for (int k = 0; k < HID; ++k) hd = fmaf(ce_s[k], Ws[k * HID + lane], hd);
        hd = fmaxf(hd, 0.f);
        float v = wr_sum(hd * Wo[lane]);
        if (lane == 0) out[c] = v + bo[0];
    }
}

extern "C" void kernel_launch(void* const* d_in, const int* in_sizes, int n_in,
                              void* d_out, int out_size, void* d_ws, size_t ws_size,
                              hipStream_t stream) {
    const float* nf  = (const float*)d_in[0];
    const float* adj = (const float*)d_in[1];
    const float* pm  = (const float*)d_in[2];
    const float* W1  = (const float*)d_in[3];
    const float* as1 = (const float*)d_in[4];
    const float* ad1 = (const float*)d_in[5];
    const float* g1  = (const float*)d_in[6];
    const float* b1  = (const float*)d_in[7];
    const float* W2  = (const float*)d_in[8];
    const float* as2 = (const float*)d_in[9];
    const float* ad2 = (const float*)d_in[10];
    const float* g2  = (const float*)d_in[11];
    const float* b2  = (const float*)d_in[12];
    const float* Wsc = (const float*)d_in[13];
    const float* bsc = (const float*)d_in[14];
    const float* Wo  = (const float*)d_in[15];
    const float* bo  = (const float*)d_in[16];
    float* outp = (float*)d_out;
    float* wsp  = (float*)d_ws;

    float* p = wsp;
    float* h1  = p; p += (size_t)N * F1;
    float* s1  = p; p += (size_t)N * HEADS;
    float* d1  = p; p += (size_t)N * HEADS;
    float* x1  = p; p += (size_t)N * F1;
    float* h2  = p; p += (size_t)N * F1;
    float* s2  = p; p += (size_t)N * HEADS;
    float* d2  = p; p += (size_t)N * HEADS;
    float* x2  = p; p += (size_t)N * HID;
    int* cnt = (int*)p;
    int* idx = cnt + N;

    void* args[] = {(void*)&adj, (void*)&nf, (void*)&pm, (void*)&W1, (void*)&as1, (void*)&ad1,
                    (void*)&g1, (void*)&b1, (void*)&W2, (void*)&as2, (void*)&ad2, (void*)&g2,
                    (void*)&b2, (void*)&Wsc, (void*)&bsc, (void*)&Wo, (void*)&bo,
                    (void*)&outp, (void*)&wsp};
    hipError_t err = hipLaunchCooperativeKernel(k_all, dim3(BLKS), dim3(256), args, 0, stream);
    if (err != hipSuccess) {
        // fallback: known-good 6-kernel pipeline (deterministic -> same path every call)
        f_build<<<N / 4, 256, 0, stream>>>(adj, cnt, idx);
        f_gemm1<<<N / RPB, 256, 0, stream>>>(nf, W1, as1, ad1, h1, s1, d1);
        f_agg1<<<N, 256, 0, stream>>>(h1, s1, d1, cnt, idx, g1, b1, x1);
        f_gemm2<<<N / RPB, 256, 0, stream>>>(x1, W2, as2, ad2, h2, s2, d2);
        f_agg2<<<N, 256, 0, stream>>>(h2, s2, d2, cnt, idx, g2, b2, x2);
        f_poolscore<<<C, 256, 0, stream>>>(pm, x2, Wsc, bsc, Wo, bo, outp);
    }
}

// Round 7
// 253.570 us; speedup vs baseline: 1.8550x; 1.8550x over previous
//
#include <hip/hip_runtime.h>
#include <math.h>

#define N 4096
#define C 512
#define EMB 38
#define HEADS 4
#define HID 64
#define F1 256       // HEADS*HID
#define MAXN 128     // max neighbors per row (p=0.01 -> mean 41, >13 sigma headroom)
#define RPB 8        // rows per block in gemms
#define BUILD_BLKS (N / 4)   // wave per row, 4 waves/block

__device__ __forceinline__ float wr_sum(float v) {
#pragma unroll
    for (int o = 32; o > 0; o >>= 1) v += __shfl_xor(v, o);
    return v;
}
__device__ __forceinline__ float wr_max(float v) {
#pragma unroll
    for (int o = 32; o > 0; o >>= 1) v = fmaxf(v, __shfl_xor(v, o));
    return v;
}

// ---------------- merged: CSR build (blocks 0..1023) || embed+gemm1 (blocks 1024..1535) ----------------
// both branches are register-lean; launch_bounds(256,4) caps VGPR at 128 so the
// scan side keeps >=4 blocks/CU for latency hiding (R3 lesson: 164 VGPR killed it)
__global__ __launch_bounds__(256, 4) void k_bg(const float* __restrict__ adj,
                                               int* __restrict__ cnt, int* __restrict__ idx,
                                               const float* __restrict__ nf, const float* __restrict__ W1,
                                               const float* __restrict__ asrc, const float* __restrict__ adst,
                                               float* __restrict__ h1, float* __restrict__ s1, float* __restrict__ d1) {
    int tid = threadIdx.x;
    int wv = tid >> 6, lane = tid & 63;
    if (blockIdx.x < BUILD_BLKS) {
        // ---- adjacency scan: wave per row, ballot compaction, prefetched ----
        int i = blockIdx.x * 4 + wv;
        const float4* row = (const float4*)(adj + (size_t)i * N);
        unsigned long long below = (lane == 63) ? (~0ull >> 1) : ((1ull << lane) - 1);
        int base = 0;
        int* orow = idx + i * MAXN;
        float4 nxt = row[lane];
        for (int it = 0; it < 16; ++it) {
            float4 a = nxt;
            if (it < 15) nxt = row[(it + 1) * 64 + lane];   // prefetch breaks load->ballot chain
            int col0 = 4 * (it * 64 + lane);
            float vals[4] = {a.x, a.y, a.z, a.w};
#pragma unroll
            for (int comp = 0; comp < 4; ++comp) {
                unsigned long long m = __ballot(vals[comp] > 0.f);
                if (vals[comp] > 0.f) {
                    int p = base + __popcll(m & below);
                    if (p < MAXN) orow[p] = col0 + comp;
                }
                base += __popcll(m);
            }
        }
        if (lane == 0) cnt[i] = min(base, MAXN);
        return;
    }
    // ---- embed + gemm1 for 8 rows ----
    int n0 = (blockIdx.x - BUILD_BLKS) * RPB;
    __shared__ float fs[RPB][8];
    __shared__ float xs[RPB][40];          // EMB=38 padded to 40, tail zeroed
    if (tid < RPB * 8) fs[tid >> 3][tid & 7] = nf[(size_t)n0 * 8 + tid];
    if (tid < RPB * 2) xs[tid >> 1][38 + (tid & 1)] = 0.f;
    __syncthreads();
    {
        int r = tid & 7;
        int t = tid >> 3;               // 0..31
        const float* f = fs[r];
        for (int pass = 0; pass < 2; ++pass, t += 32) {
            if (t >= EMB) break;
            float val;
            if (t < 6) { int nt = min(max((int)f[0], 0), 5); val = (t == nt) ? 1.f : 0.f; }
            else if (t == 6) val = log1pf(f[1]);
            else if (t < 31) {
                int q = (t - 7) & 7, s = (t - 7) >> 3, m = q >> 1;
                float base = (s == 0) ? f[2] : (s == 1) ? f[3] : f[4] * 100.f;
                float div = expf((2.f * m) * (-logf(10000.f) / 8.f));
                float sc = base * div;
                val = (q & 1) ? cosf(sc) : sinf(sc);
            }
            else if (t < 36) { int role = min(max((int)f[5], 0), 4); val = (t - 31 == role) ? 1.f : 0.f; }
            else val = (t == 36) ? f[6] : f[7];
            xs[r][t] = val;
        }
    }
    __syncthreads();
    float acc[RPB];
#pragma unroll
    for (int r = 0; r < RPB; ++r) acc[r] = 0.f;
#pragma unroll
    for (int kk = 0; kk < 9; ++kk) {      // k = 0..35 via float4 LDS broadcast
        float w0 = W1[(4 * kk + 0) * F1 + tid];
        float w1 = W1[(4 * kk + 1) * F1 + tid];
        float w2 = W1[(4 * kk + 2) * F1 + tid];
        float w3 = W1[(4 * kk + 3) * F1 + tid];
#pragma unroll
        for (int r = 0; r < RPB; ++r) {
            float4 x = *(const float4*)&xs[r][4 * kk];
            acc[r] = fmaf(x.x, w0, fmaf(x.y, w1, fmaf(x.z, w2, fmaf(x.w, w3, acc[r]))));
        }
    }
#pragma unroll
    for (int k = 36; k < EMB; ++k) {      // tail
        float wvv = W1[k * F1 + tid];
#pragma unroll
        for (int r = 0; r < RPB; ++r) acc[r] = fmaf(xs[r][k], wvv, acc[r]);
    }
    float av = asrc[tid], dv = adst[tid];
#pragma unroll
    for (int r = 0; r < RPB; ++r) {
        h1[(size_t)(n0 + r) * F1 + tid] = acc[r];
        float ss = wr_sum(acc[r] * av);
        float dd = wr_sum(acc[r] * dv);
        if (lane == 0) { s1[(n0 + r) * HEADS + wv] = ss; d1[(n0 + r) * HEADS + wv] = dd; }
    }
}

// ---------------- GEMM2 [N,256]@[256,256] + fused attention dots (float4 LDS) ----------------
__global__ __launch_bounds__(256) void k_gemm2(const float* __restrict__ x1, const float* __restrict__ W2,
                                               const float* __restrict__ asrc, const float* __restrict__ adst,
                                               float* __restrict__ h2, float* __restrict__ s2, float* __restrict__ d2) {
    int n0 = blockIdx.x * RPB, tid = threadIdx.x;
    __shared__ float4 xs4[RPB][F1 / 4];
    {
        int r = tid >> 5, kk = tid & 31;
        const float4* x1v = (const float4*)x1;
        xs4[r][kk]      = x1v[(size_t)(n0 + r) * 64 + kk];
        xs4[r][kk + 32] = x1v[(size_t)(n0 + r) * 64 + kk + 32];
    }
    __syncthreads();
    float acc[RPB];
#pragma unroll
    for (int r = 0; r < RPB; ++r) acc[r] = 0.f;
    for (int kk = 0; kk < F1 / 4; ++kk) {
        float w0 = W2[(4 * kk + 0) * F1 + tid];
        float w1 = W2[(4 * kk + 1) * F1 + tid];
        float w2 = W2[(4 * kk + 2) * F1 + tid];
        float w3 = W2[(4 * kk + 3) * F1 + tid];
#pragma unroll
        for (int r = 0; r < RPB; ++r) {
            float4 x = xs4[r][kk];
            acc[r] = fmaf(x.x, w0, fmaf(x.y, w1, fmaf(x.z, w2, fmaf(x.w, w3, acc[r]))));
        }
    }
    int h = tid >> 6, lane = tid & 63;
    float av = asrc[tid], dv = adst[tid];
#pragma unroll
    for (int r = 0; r < RPB; ++r) {
        h2[(size_t)(n0 + r) * F1 + tid] = acc[r];
        float ss = wr_sum(acc[r] * av);
        float dd = wr_sum(acc[r] * dv);
        if (lane == 0) { s2[(n0 + r) * HEADS + h] = ss; d2[(n0 + r) * HEADS + h] = dd; }
    }
}

// ---------------- GAT aggregation layer 1 (concat) + LN(256) + ELU: 4-deep wave-split gather ----------------
__global__ __launch_bounds__(256) void k_agg1(const float* __restrict__ h1, const float* __restrict__ s1,
                                              const float* __restrict__ d1, const int* __restrict__ cnt,
                                              const int* __restrict__ idx, const float* __restrict__ g,
                                              const float* __restrict__ b, float* __restrict__ xo) {
    int i = blockIdx.x, tid = threadIdx.x;
    int wv = tid >> 6, lane = tid & 63;
    __shared__ int nbrs[MAXN];
    __shared__ float wts[HEADS][MAXN + 1];
    __shared__ float lsum[HEADS];
    __shared__ float sacc[4][F1];
    __shared__ float red[HEADS];
    int c = cnt[i];
    if (tid < c) nbrs[tid] = idx[i * MAXN + tid];
    __syncthreads();
    if (tid < c) {
        float4 dd = ((const float4*)d1)[nbrs[tid]];
        float4 ss = ((const float4*)s1)[i];
        float e0 = ss.x + dd.x, e1 = ss.y + dd.y, e2 = ss.z + dd.z, e3 = ss.w + dd.w;
        wts[0][tid] = e0 > 0.f ? e0 : 0.2f * e0;
        wts[1][tid] = e1 > 0.f ? e1 : 0.2f * e1;
        wts[2][tid] = e2 > 0.f ? e2 : 0.2f * e2;
        wts[3][tid] = e3 > 0.f ? e3 : 0.2f * e3;
    }
    __syncthreads();
    {   // per-head softmax normalize: wave wv owns head wv
        float m = -INFINITY;
        for (int jj = lane; jj < c; jj += 64) m = fmaxf(m, wts[wv][jj]);
        m = wr_max(m);
        float l = 0.f;
        for (int jj = lane; jj < c; jj += 64) { float t = expf(wts[wv][jj] - m); wts[wv][jj] = t; l += t; }
        l = wr_sum(l);
        if (lane == 0) lsum[wv] = l;
    }
    __syncthreads();
    // gather: wave wv takes neighbors wv, wv+4, ... ; lane owns cols 4*lane..4*lane+3
    int hq = lane >> 4;
    const float4* hv = (const float4*)h1;
    float4 acc = {0.f, 0.f, 0.f, 0.f};
    int jj = wv;
    for (; jj + 12 < c; jj += 16) {   // 4 loads in flight
        int na = nbrs[jj], nb = nbrs[jj + 4], nc = nbrs[jj + 8], nd = nbrs[jj + 12];
        float wa = wts[hq][jj], wb = wts[hq][jj + 4], wc = wts[hq][jj + 8], wd = wts[hq][jj + 12];
        float4 va = hv[(size_t)na * 64 + lane];
        float4 vb = hv[(size_t)nb * 64 + lane];
        float4 vc = hv[(size_t)nc * 64 + lane];
        float4 vd = hv[(size_t)nd * 64 + lane];
        acc.x = fmaf(wa, va.x, acc.x); acc.y = fmaf(wa, va.y, acc.y);
        acc.z = fmaf(wa, va.z, acc.z); acc.w = fmaf(wa, va.w, acc.w);
        acc.x = fmaf(wb, vb.x, acc.x); acc.y = fmaf(wb, vb.y, acc.y);
        acc.z = fmaf(wb, vb.z, acc.z); acc.w = fmaf(wb, vb.w, acc.w);
        acc.x = fmaf(wc, vc.x, acc.x); acc.y = fmaf(wc, vc.y, acc.y);
        acc.z = fmaf(wc, vc.z, acc.z); acc.w = fmaf(wc, vc.w, acc.w);
        acc.x = fmaf(wd, vd.x, acc.x); acc.y = fmaf(wd, vd.y, acc.y);
        acc.z = fmaf(wd, vd.z, acc.z); acc.w = fmaf(wd, vd.w, acc.w);
    }
    for (; jj < c; jj += 4) {
        int na = nbrs[jj];
        float wa = wts[hq][jj];
        float4 va = hv[(size_t)na * 64 + lane];
        acc.x = fmaf(wa, va.x, acc.x); acc.y = fmaf(wa, va.y, acc.y);
        acc.z = fmaf(wa, va.z, acc.z); acc.w = fmaf(wa, va.w, acc.w);
    }
    ((float4*)&sacc[wv][0])[lane] = acc;
    __syncthreads();
    // combine + LN(256) + ELU
    float tot = (sacc[0][tid] + sacc[1][tid] + sacc[2][tid] + sacc[3][tid]) / lsum[wv];
    float s = wr_sum(tot);
    if (lane == 0) red[wv] = s;
    __syncthreads();
    float mu = (red[0] + red[1] + red[2] + red[3]) * (1.f / F1);
    float dvv = tot - mu;
    float s2 = wr_sum(dvv * dvv);
    __syncthreads();
    if (lane == 0) red[wv] = s2;
    __syncthreads();
    float var = (red[0] + red[1] + red[2] + red[3]) * (1.f / F1);
    float y = dvv * rsqrtf(var + 1e-5f) * g[tid] + b[tid];
    xo[(size_t)i * F1 + tid] = y > 0.f ? y : expm1f(y);
}

// ---------------- GAT aggregation layer 2 (mean heads) + LN(64) + ELU: 4-deep wave-split gather ----------------
__global__ __launch_bounds__(256) void k_agg2(const float* __restrict__ h2, const float* __restrict__ s2,
                                              const float* __restrict__ d2, const int* __restrict__ cnt,
                                              const int* __restrict__ idx, const float* __restrict__ g,
                                              const float* __restrict__ b, float* __restrict__ xo) {
    int i = blockIdx.x, tid = threadIdx.x;
    int wv = tid >> 6, lane = tid & 63;
    __shared__ int nbrs[MAXN];
    __shared__ float wts[HEADS][MAXN + 1];
    __shared__ float lsum[HEADS];
    __shared__ float sacc[4][F1];
    int c = cnt[i];
    if (tid < c) nbrs[tid] = idx[i * MAXN + tid];
    __syncthreads();
    if (tid < c) {
        float4 dd = ((const float4*)d2)[nbrs[tid]];
        float4 ss = ((const float4*)s2)[i];
        float e0 = ss.x + dd.x, e1 = ss.y + dd.y, e2 = ss.z + dd.z, e3 = ss.w + dd.w;
        wts[0][tid] = e0 > 0.f ? e0 : 0.2f * e0;
        wts[1][tid] = e1 > 0.f ? e1 : 0.2f * e1;
        wts[2][tid] = e2 > 0.f ? e2 : 0.2f * e2;
        wts[3][tid] = e3 > 0.f ? e3 : 0.2f * e3;
    }
    __syncthreads();
    {
        float m = -INFINITY;
        for (int jj = lane; jj < c; jj += 64) m = fmaxf(m, wts[wv][jj]);
        m = wr_max(m);
        float l = 0.f;
        for (int jj = lane; jj < c; jj += 64) { float t = expf(wts[wv][jj] - m); wts[wv][jj] = t; l += t; }
        l = wr_sum(l);
        if (lane == 0) lsum[wv] = l;
    }
    __syncthreads();
    int hq = lane >> 4;
    const float4* hvv = (const float4*)h2;
    float4 acc = {0.f, 0.f, 0.f, 0.f};
    int jj = wv;
    for (; jj + 12 < c; jj += 16) {
        int na = nbrs[jj], nb = nbrs[jj + 4], nc = nbrs[jj + 8], nd = nbrs[jj + 12];
        float wa = wts[hq][jj], wb = wts[hq][jj + 4], wc = wts[hq][jj + 8], wd = wts[hq][jj + 12];
        float4 va = hvv[(size_t)na * 64 + lane];
        float4 vb = hvv[(size_t)nb * 64 + lane];
        float4 vc = hvv[(size_t)nc * 64 + lane];
        float4 vd = hvv[(size_t)nd * 64 + lane];
        acc.x = fmaf(wa, va.x, acc.x); acc.y = fmaf(wa, va.y, acc.y);
        acc.z = fmaf(wa, va.z, acc.z); acc.w = fmaf(wa, va.w, acc.w);
        acc.x = fmaf(wb, vb.x, acc.x); acc.y = fmaf(wb, vb.y, acc.y);
        acc.z = fmaf(wb, vb.z, acc.z); acc.w = fmaf(wb, vb.w, acc.w);
        acc.x = fmaf(wc, vc.x, acc.x); acc.y = fmaf(wc, vc.y, acc.y);
        acc.z = fmaf(wc, vc.z, acc.z); acc.w = fmaf(wc, vc.w, acc.w);
        acc.x = fmaf(wd, vd.x, acc.x); acc.y = fmaf(wd, vd.y, acc.y);
        acc.z = fmaf(wd, vd.z, acc.z); acc.w = fmaf(wd, vd.w, acc.w);
    }
    for (; jj < c; jj += 4) {
        int na = nbrs[jj];
        float wa = wts[hq][jj];
        float4 va = hvv[(size_t)na * 64 + lane];
        acc.x = fmaf(wa, va.x, acc.x); acc.y = fmaf(wa, va.y, acc.y);
        acc.z = fmaf(wa, va.z, acc.z); acc.w = fmaf(wa, va.w, acc.w);
    }
    ((float4*)&sacc[wv][0])[lane] = acc;
    __syncthreads();
    // combine partials, mean over heads, LN(64), ELU — one wave
    if (wv == 0) {
        float t0 = 0.f, t1 = 0.f, t2 = 0.f, t3 = 0.f;
#pragma unroll
        for (int w = 0; w < 4; ++w) {
            t0 += sacc[w][lane];
            t1 += sacc[w][lane + 64];
            t2 += sacc[w][lane + 128];
            t3 += sacc[w][lane + 192];
        }
        float mv = (t0 / lsum[0] + t1 / lsum[1] + t2 / lsum[2] + t3 / lsum[3]) * 0.25f;
        float mu = wr_sum(mv) * (1.f / HID);
        float dvv = mv - mu;
        float var = wr_sum(dvv * dvv) * (1.f / HID);
        float y = dvv * rsqrtf(var + 1e-5f) * g[lane] + b[lane];
        xo[i * HID + lane] = y > 0.f ? y : expm1f(y);
    }
}

// ---------------- fused clause pooling + scorer ----------------
__global__ __launch_bounds__(256) void k_poolscore(const float* __restrict__ pm, const float* __restrict__ x2,
                                                   const float* __restrict__ Ws, const float* __restrict__ bs,
                                                   const float* __restrict__ Wo, const float* __restrict__ bo,
                                                   float* __restrict__ out) {
    int c = blockIdx.x, tid = threadIdx.x;
    int w = tid >> 6, lane = tid & 63;
    __shared__ float sacc[4][HID];
    __shared__ float ce_s[HID];
    float acc = 0.f;
    const float4* pmv = (const float4*)(pm + (size_t)c * N);
#pragma unroll
    for (int it = 0; it < 4; ++it) {
        int vi = w * 256 + it * 64 + lane;   // float4 index into the pm row
        float4 p4 = pmv[vi];
        float pc[4] = {p4.x, p4.y, p4.z, p4.w};
#pragma unroll
        for (int comp = 0; comp < 4; ++comp) {
            unsigned long long msk = __ballot(pc[comp] != 0.f);
            while (msk) {
                int bpos = __ffsll(msk) - 1;
                msk &= msk - 1;
                float pj = __shfl(pc[comp], bpos);
                int j = (w * 256 + it * 64 + bpos) * 4 + comp;
                acc += pj * x2[(size_t)j * HID + lane];
            }
        }
    }
    sacc[w][lane] = acc;
    __syncthreads();
    if (w == 0) ce_s[lane] = sacc[0][lane] + sacc[1][lane] + sacc[2][lane] + sacc[3][lane];
    __syncthreads();
    if (w == 0) {
        float hd = bs[lane];
#pragma unroll 8
        for (int k = 0; k < HID; ++k) hd = fmaf(ce_s[k], Ws[k * HID + lane], hd);
        hd = fmaxf(hd, 0.f);
        float v = wr_sum(hd * Wo[lane]);
        if (lane == 0) out[c] = v + bo[0];
    }
}

extern "C" void kernel_launch(void* const* d_in, const int* in_sizes, int n_in,
                              void* d_out, int out_size, void* d_ws, size_t ws_size,
                              hipStream_t stream) {
    const float* nf  = (const float*)d_in[0];
    const float* adj = (const float*)d_in[1];
    const float* pm  = (const float*)d_in[2];
    const float* W1  = (const float*)d_in[3];
    const float* as1 = (const float*)d_in[4];
    const float* ad1 = (const float*)d_in[5];
    const float* g1  = (const float*)d_in[6];
    const float* b1  = (const float*)d_in[7];
    const float* W2  = (const float*)d_in[8];
    const float* as2 = (const float*)d_in[9];
    const float* ad2 = (const float*)d_in[10];
    const float* g2  = (const float*)d_in[11];
    const float* b2  = (const float*)d_in[12];
    const float* Ws  = (const float*)d_in[13];
    const float* bs  = (const float*)d_in[14];
    const float* Wo  = (const float*)d_in[15];
    const float* bo  = (const float*)d_in[16];
    float* out = (float*)d_out;

    float* p = (float*)d_ws;
    float* h1  = p; p += (size_t)N * F1;
    float* s1  = p; p += (size_t)N * HEADS;
    float* d1  = p; p += (size_t)N * HEADS;
    float* x1  = p; p += (size_t)N * F1;
    float* h2  = p; p += (size_t)N * F1;
    float* s2  = p; p += (size_t)N * HEADS;
    float* d2  = p; p += (size_t)N * HEADS;
    float* x2  = p; p += (size_t)N * HID;
    int* cnt = (int*)p;
    int* idx = cnt + N;

    k_bg<<<BUILD_BLKS + N / RPB, 256, 0, stream>>>(adj, cnt, idx, nf, W1, as1, ad1, h1, s1, d1);
    k_agg1<<<N, 256, 0, stream>>>(h1, s1, d1, cnt, idx, g1, b1, x1);
    k_gemm2<<<N / RPB, 256, 0, stream>>>(x1, W2, as2, ad2, h2, s2, d2);
    k_agg2<<<N, 256, 0, stream>>>(h2, s2, d2, cnt, idx, g2, b2, x2);
    k_poolscore<<<C, 256, 0, stream>>>(pm, x2, Ws, bs, Wo, bo, out);
}

// Round 8
// 200.410 us; speedup vs baseline: 2.3470x; 1.2653x over previous
//
#include <hip/hip_runtime.h>
#include <math.h>

#define N 4096
#define C 512
#define EMB 38
#define HEADS 4
#define HID 64
#define F1 256       // HEADS*HID
#define MAXN 128     // max neighbors per row (p=0.01 -> mean 41, >13 sigma headroom)
#define RPB 8        // rows per block in gemms

__device__ __forceinline__ float wr_sum(float v) {
#pragma unroll
    for (int o = 32; o > 0; o >>= 1) v += __shfl_xor(v, o);
    return v;
}
__device__ __forceinline__ float wr_max(float v) {
#pragma unroll
    for (int o = 32; o > 0; o >>= 1) v = fmaxf(v, __shfl_xor(v, o));
    return v;
}

// ---------------- build CSR: wave per row; compact in LDS, write global COALESCED ----------------
// R7 lesson: per-lane scattered global stores (42 active lanes over 64 exec-masked store
// instrs/row) caused L2 write-allocate RMW amplification (FETCH+20MB, WRITE+100MB) and a
// latency-bound kernel at 28% HBM. LDS staging makes the global write 2 coalesced stores/row.
__global__ void k_build(const float* __restrict__ adj,
                        int* __restrict__ cnt, int* __restrict__ idx) {
    int wv = threadIdx.x >> 6, lane = threadIdx.x & 63;
    int i = blockIdx.x * 4 + wv;
    __shared__ int stage[4][MAXN];
    const float4* row = (const float4*)(adj + (size_t)i * N);
    unsigned long long below = (1ull << lane) - 1;
    int base = 0;
    float4 nxt = row[lane];
    for (int it = 0; it < 16; ++it) {
        float4 a = nxt;
        if (it < 15) nxt = row[(it + 1) * 64 + lane];   // prefetch breaks load->ballot chain
        int col0 = 4 * (it * 64 + lane);
        float vals[4] = {a.x, a.y, a.z, a.w};
#pragma unroll
        for (int comp = 0; comp < 4; ++comp) {
            unsigned long long m = __ballot(vals[comp] > 0.f);
            if (vals[comp] > 0.f) {
                int p = base + __popcll(m & below);
                if (p < MAXN) stage[wv][p] = col0 + comp;   // LDS scatter: contiguous -> conflict-free
            }
            base += __popcll(m);
        }
    }
    int c = min(base, MAXN);
    __syncthreads();
    if (lane < c)      idx[i * MAXN + lane]      = stage[wv][lane];
    if (lane + 64 < c) idx[i * MAXN + lane + 64] = stage[wv][lane + 64];
    if (lane == 0) cnt[i] = c;
}

// ---------------- fused embed + GEMM1 [8 nodes/block: 38->256] + attention dots ----------------
__global__ __launch_bounds__(256) void k_gemm1(const float* __restrict__ nf, const float* __restrict__ W1,
                                               const float* __restrict__ asrc, const float* __restrict__ adst,
                                               float* __restrict__ h1, float* __restrict__ s1, float* __restrict__ d1) {
    int n0 = blockIdx.x * RPB, tid = threadIdx.x;
    __shared__ float fs[RPB][8];
    __shared__ float xs[RPB][40];          // EMB=38 padded to 40, tail zeroed
    if (tid < RPB * 8) fs[tid >> 3][tid & 7] = nf[(size_t)n0 * 8 + tid];
    if (tid < RPB * 2) xs[tid >> 1][38 + (tid & 1)] = 0.f;
    __syncthreads();
    {
        int r = tid & 7;
        int t = tid >> 3;               // 0..31
        const float* f = fs[r];
        for (int pass = 0; pass < 2; ++pass, t += 32) {
            if (t >= EMB) break;
            float val;
            if (t < 6) { int nt = min(max((int)f[0], 0), 5); val = (t == nt) ? 1.f : 0.f; }
            else if (t == 6) val = log1pf(f[1]);
            else if (t < 31) {
                int q = (t - 7) & 7, s = (t - 7) >> 3, m = q >> 1;
                float base = (s == 0) ? f[2] : (s == 1) ? f[3] : f[4] * 100.f;
                float div = expf((2.f * m) * (-logf(10000.f) / 8.f));
                float sc = base * div;
                val = (q & 1) ? cosf(sc) : sinf(sc);
            }
            else if (t < 36) { int role = min(max((int)f[5], 0), 4); val = (t - 31 == role) ? 1.f : 0.f; }
            else val = (t == 36) ? f[6] : f[7];
            xs[r][t] = val;
        }
    }
    __syncthreads();
    float acc[RPB];
#pragma unroll
    for (int r = 0; r < RPB; ++r) acc[r] = 0.f;
#pragma unroll
    for (int kk = 0; kk < 9; ++kk) {      // k = 0..35 via float4 LDS broadcast
        float w0 = W1[(4 * kk + 0) * F1 + tid];
        float w1 = W1[(4 * kk + 1) * F1 + tid];
        float w2 = W1[(4 * kk + 2) * F1 + tid];
        float w3 = W1[(4 * kk + 3) * F1 + tid];
#pragma unroll
        for (int r = 0; r < RPB; ++r) {
            float4 x = *(const float4*)&xs[r][4 * kk];
            acc[r] = fmaf(x.x, w0, fmaf(x.y, w1, fmaf(x.z, w2, fmaf(x.w, w3, acc[r]))));
        }
    }
#pragma unroll
    for (int k = 36; k < EMB; ++k) {      // tail
        float wvv = W1[k * F1 + tid];
#pragma unroll
        for (int r = 0; r < RPB; ++r) acc[r] = fmaf(xs[r][k], wvv, acc[r]);
    }
    int h = tid >> 6, lane = tid & 63;
    float av = asrc[tid], dv = adst[tid];
#pragma unroll
    for (int r = 0; r < RPB; ++r) {
        h1[(size_t)(n0 + r) * F1 + tid] = acc[r];
        float ss = wr_sum(acc[r] * av);
        float dd = wr_sum(acc[r] * dv);
        if (lane == 0) { s1[(n0 + r) * HEADS + h] = ss; d1[(n0 + r) * HEADS + h] = dd; }
    }
}

// ---------------- GEMM2 [N,256]@[256,256] + fused attention dots (float4 LDS) ----------------
__global__ __launch_bounds__(256) void k_gemm2(const float* __restrict__ x1, const float* __restrict__ W2,
                                               const float* __restrict__ asrc, const float* __restrict__ adst,
                                               float* __restrict__ h2, float* __restrict__ s2, float* __restrict__ d2) {
    int n0 = blockIdx.x * RPB, tid = threadIdx.x;
    __shared__ float4 xs4[RPB][F1 / 4];
    {
        int r = tid >> 5, kk = tid & 31;
        const float4* x1v = (const float4*)x1;
        xs4[r][kk]      = x1v[(size_t)(n0 + r) * 64 + kk];
        xs4[r][kk + 32] = x1v[(size_t)(n0 + r) * 64 + kk + 32];
    }
    __syncthreads();
    float acc[RPB];
#pragma unroll
    for (int r = 0; r < RPB; ++r) acc[r] = 0.f;
    for (int kk = 0; kk < F1 / 4; ++kk) {
        float w0 = W2[(4 * kk + 0) * F1 + tid];
        float w1 = W2[(4 * kk + 1) * F1 + tid];
        float w2 = W2[(4 * kk + 2) * F1 + tid];
        float w3 = W2[(4 * kk + 3) * F1 + tid];
#pragma unroll
        for (int r = 0; r < RPB; ++r) {
            float4 x = xs4[r][kk];
            acc[r] = fmaf(x.x, w0, fmaf(x.y, w1, fmaf(x.z, w2, fmaf(x.w, w3, acc[r]))));
        }
    }
    int h = tid >> 6, lane = tid & 63;
    float av = asrc[tid], dv = adst[tid];
#pragma unroll
    for (int r = 0; r < RPB; ++r) {
        h2[(size_t)(n0 + r) * F1 + tid] = acc[r];
        float ss = wr_sum(acc[r] * av);
        float dd = wr_sum(acc[r] * dv);
        if (lane == 0) { s2[(n0 + r) * HEADS + h] = ss; d2[(n0 + r) * HEADS + h] = dd; }
    }
}

// ---------------- GAT aggregation layer 1 (concat) + LN(256) + ELU: 4-deep wave-split gather ----------------
__global__ __launch_bounds__(256) void k_agg1(const float* __restrict__ h1, const float* __restrict__ s1,
                                              const float* __restrict__ d1, const int* __restrict__ cnt,
                                              const int* __restrict__ idx, const float* __restrict__ g,
                                              const float* __restrict__ b, float* __restrict__ xo) {
    int i = blockIdx.x, tid = threadIdx.x;
    int wv = tid >> 6, lane = tid & 63;
    __shared__ int nbrs[MAXN];
    __shared__ float wts[HEADS][MAXN + 1];
    __shared__ float lsum[HEADS];
    __shared__ float sacc[4][F1];
    __shared__ float red[HEADS];
    int c = cnt[i];
    if (tid < c) nbrs[tid] = idx[i * MAXN + tid];
    __syncthreads();
    if (tid < c) {
        float4 dd = ((const float4*)d1)[nbrs[tid]];
        float4 ss = ((const float4*)s1)[i];
        float e0 = ss.x + dd.x, e1 = ss.y + dd.y, e2 = ss.z + dd.z, e3 = ss.w + dd.w;
        wts[0][tid] = e0 > 0.f ? e0 : 0.2f * e0;
        wts[1][tid] = e1 > 0.f ? e1 : 0.2f * e1;
        wts[2][tid] = e2 > 0.f ? e2 : 0.2f * e2;
        wts[3][tid] = e3 > 0.f ? e3 : 0.2f * e3;
    }
    __syncthreads();
    {   // per-head softmax normalize: wave wv owns head wv
        float m = -INFINITY;
        for (int jj = lane; jj < c; jj += 64) m = fmaxf(m, wts[wv][jj]);
        m = wr_max(m);
        float l = 0.f;
        for (int jj = lane; jj < c; jj += 64) { float t = expf(wts[wv][jj] - m); wts[wv][jj] = t; l += t; }
        l = wr_sum(l);
        if (lane == 0) lsum[wv] = l;
    }
    __syncthreads();
    int hq = lane >> 4;
    const float4* hv = (const float4*)h1;
    float4 acc = {0.f, 0.f, 0.f, 0.f};
    int jj = wv;
    for (; jj + 12 < c; jj += 16) {   // 4 loads in flight
        int na = nbrs[jj], nb = nbrs[jj + 4], nc = nbrs[jj + 8], nd = nbrs[jj + 12];
        float wa = wts[hq][jj], wb = wts[hq][jj + 4], wc = wts[hq][jj + 8], wd = wts[hq][jj + 12];
        float4 va = hv[(size_t)na * 64 + lane];
        float4 vb = hv[(size_t)nb * 64 + lane];
        float4 vc = hv[(size_t)nc * 64 + lane];
        float4 vd = hv[(size_t)nd * 64 + lane];
        acc.x = fmaf(wa, va.x, acc.x); acc.y = fmaf(wa, va.y, acc.y);
        acc.z = fmaf(wa, va.z, acc.z); acc.w = fmaf(wa, va.w, acc.w);
        acc.x = fmaf(wb, vb.x, acc.x); acc.y = fmaf(wb, vb.y, acc.y);
        acc.z = fmaf(wb, vb.z, acc.z); acc.w = fmaf(wb, vb.w, acc.w);
        acc.x = fmaf(wc, vc.x, acc.x); acc.y = fmaf(wc, vc.y, acc.y);
        acc.z = fmaf(wc, vc.z, acc.z); acc.w = fmaf(wc, vc.w, acc.w);
        acc.x = fmaf(wd, vd.x, acc.x); acc.y = fmaf(wd, vd.y, acc.y);
        acc.z = fmaf(wd, vd.z, acc.z); acc.w = fmaf(wd, vd.w, acc.w);
    }
    for (; jj < c; jj += 4) {
        int na = nbrs[jj];
        float wa = wts[hq][jj];
        float4 va = hv[(size_t)na * 64 + lane];
        acc.x = fmaf(wa, va.x, acc.x); acc.y = fmaf(wa, va.y, acc.y);
        acc.z = fmaf(wa, va.z, acc.z); acc.w = fmaf(wa, va.w, acc.w);
    }
    ((float4*)&sacc[wv][0])[lane] = acc;
    __syncthreads();
    float tot = (sacc[0][tid] + sacc[1][tid] + sacc[2][tid] + sacc[3][tid]) / lsum[wv];
    float s = wr_sum(tot);
    if (lane == 0) red[wv] = s;
    __syncthreads();
    float mu = (red[0] + red[1] + red[2] + red[3]) * (1.f / F1);
    float dvv = tot - mu;
    float s2 = wr_sum(dvv * dvv);
    __syncthreads();
    if (lane == 0) red[wv] = s2;
    __syncthreads();
    float var = (red[0] + red[1] + red[2] + red[3]) * (1.f / F1);
    float y = dvv * rsqrtf(var + 1e-5f) * g[tid] + b[tid];
    xo[(size_t)i * F1 + tid] = y > 0.f ? y : expm1f(y);
}

// ---------------- GAT aggregation layer 2 (mean heads) + LN(64) + ELU: 4-deep wave-split gather ----------------
__global__ __launch_bounds__(256) void k_agg2(const float* __restrict__ h2, const float* __restrict__ s2,
                                              const float* __restrict__ d2, const int* __restrict__ cnt,
                                              const int* __restrict__ idx, const float* __restrict__ g,
                                              const float* __restrict__ b, float* __restrict__ xo) {
    int i = blockIdx.x, tid = threadIdx.x;
    int wv = tid >> 6, lane = tid & 63;
    __shared__ int nbrs[MAXN];
    __shared__ float wts[HEADS][MAXN + 1];
    __shared__ float lsum[HEADS];
    __shared__ float sacc[4][F1];
    int c = cnt[i];
    if (tid < c) nbrs[tid] = idx[i * MAXN + tid];
    __syncthreads();
    if (tid < c) {
        float4 dd = ((const float4*)d2)[nbrs[tid]];
        float4 ss = ((const float4*)s2)[i];
        float e0 = ss.x + dd.x, e1 = ss.y + dd.y, e2 = ss.z + dd.z, e3 = ss.w + dd.w;
        wts[0][tid] = e0 > 0.f ? e0 : 0.2f * e0;
        wts[1][tid] = e1 > 0.f ? e1 : 0.2f * e1;
        wts[2][tid] = e2 > 0.f ? e2 : 0.2f * e2;
        wts[3][tid] = e3 > 0.f ? e3 : 0.2f * e3;
    }
    __syncthreads();
    {
        float m = -INFINITY;
        for (int jj = lane; jj < c; jj += 64) m = fmaxf(m, wts[wv][jj]);
        m = wr_max(m);
        float l = 0.f;
        for (int jj = lane; jj < c; jj += 64) { float t = expf(wts[wv][jj] - m); wts[wv][jj] = t; l += t; }
        l = wr_sum(l);
        if (lane == 0) lsum[wv] = l;
    }
    __syncthreads();
    int hq = lane >> 4;
    const float4* hvv = (const float4*)h2;
    float4 acc = {0.f, 0.f, 0.f, 0.f};
    int jj = wv;
    for (; jj + 12 < c; jj += 16) {
        int na = nbrs[jj], nb = nbrs[jj + 4], nc = nbrs[jj + 8], nd = nbrs[jj + 12];
        float wa = wts[hq][jj], wb = wts[hq][jj + 4], wc = wts[hq][jj + 8], wd = wts[hq][jj + 12];
        float4 va = hvv[(size_t)na * 64 + lane];
        float4 vb = hvv[(size_t)nb * 64 + lane];
        float4 vc = hvv[(size_t)nc * 64 + lane];
        float4 vd = hvv[(size_t)nd * 64 + lane];
        acc.x = fmaf(wa, va.x, acc.x); acc.y = fmaf(wa, va.y, acc.y);
        acc.z = fmaf(wa, va.z, acc.z); acc.w = fmaf(wa, va.w, acc.w);
        acc.x = fmaf(wb, vb.x, acc.x); acc.y = fmaf(wb, vb.y, acc.y);
        acc.z = fmaf(wb, vb.z, acc.z); acc.w = fmaf(wb, vb.w, acc.w);
        acc.x = fmaf(wc, vc.x, acc.x); acc.y = fmaf(wc, vc.y, acc.y);
        acc.z = fmaf(wc, vc.z, acc.z); acc.w = fmaf(wc, vc.w, acc.w);
        acc.x = fmaf(wd, vd.x, acc.x); acc.y = fmaf(wd, vd.y, acc.y);
        acc.z = fmaf(wd, vd.z, acc.z); acc.w = fmaf(wd, vd.w, acc.w);
    }
    for (; jj < c; jj += 4) {
        int na = nbrs[jj];
        float wa = wts[hq][jj];
        float4 va = hvv[(size_t)na * 64 + lane];
        acc.x = fmaf(wa, va.x, acc.x); acc.y = fmaf(wa, va.y, acc.y);
        acc.z = fmaf(wa, va.z, acc.z); acc.w = fmaf(wa, va.w, acc.w);
    }
    ((float4*)&sacc[wv][0])[lane] = acc;
    __syncthreads();
    if (wv == 0) {
        float t0 = 0.f, t1 = 0.f, t2 = 0.f, t3 = 0.f;
#pragma unroll
        for (int w = 0; w < 4; ++w) {
            t0 += sacc[w][lane];
            t1 += sacc[w][lane + 64];
            t2 += sacc[w][lane + 128];
            t3 += sacc[w][lane + 192];
        }
        float mv = (t0 / lsum[0] + t1 / lsum[1] + t2 / lsum[2] + t3 / lsum[3]) * 0.25f;
        float mu = wr_sum(mv) * (1.f / HID);
        float dvv = mv - mu;
        float var = wr_sum(dvv * dvv) * (1.f / HID);
        float y = dvv * rsqrtf(var + 1e-5f) * g[lane] + b[lane];
        xo[i * HID + lane] = y > 0.f ? y : expm1f(y);
    }
}

// ---------------- fused clause pooling + scorer ----------------
__global__ __launch_bounds__(256) void k_poolscore(const float* __restrict__ pm, const float* __restrict__ x2,
                                                   const float* __restrict__ Ws, const float* __restrict__ bs,
                                                   const float* __restrict__ Wo, const float* __restrict__ bo,
                                                   float* __restrict__ out) {
    int c = blockIdx.x, tid = threadIdx.x;
    int w = tid >> 6, lane = tid & 63;
    __shared__ float sacc[4][HID];
    __shared__ float ce_s[HID];
    float acc = 0.f;
    const float4* pmv = (const float4*)(pm + (size_t)c * N);
#pragma unroll
    for (int it = 0; it < 4; ++it) {
        int vi = w * 256 + it * 64 + lane;   // float4 index into the pm row
        float4 p4 = pmv[vi];
        float pc[4] = {p4.x, p4.y, p4.z, p4.w};
#pragma unroll
        for (int comp = 0; comp < 4; ++comp) {
            unsigned long long msk = __ballot(pc[comp] != 0.f);
            while (msk) {
                int bpos = __ffsll(msk) - 1;
                msk &= msk - 1;
                float pj = __shfl(pc[comp], bpos);
                int j = (w * 256 + it * 64 + bpos) * 4 + comp;
                acc += pj * x2[(size_t)j * HID + lane];
            }
        }
    }
    sacc[w][lane] = acc;
    __syncthreads();
    if (w == 0) ce_s[lane] = sacc[0][lane] + sacc[1][lane] + sacc[2][lane] + sacc[3][lane];
    __syncthreads();
    if (w == 0) {
        float hd = bs[lane];
#pragma unroll 8
        for (int k = 0; k < HID; ++k) hd = fmaf(ce_s[k], Ws[k * HID + lane], hd);
        hd = fmaxf(hd, 0.f);
        float v = wr_sum(hd * Wo[lane]);
        if (lane == 0) out[c] = v + bo[0];
    }
}

extern "C" void kernel_launch(void* const* d_in, const int* in_sizes, int n_in,
                              void* d_out, int out_size, void* d_ws, size_t ws_size,
                              hipStream_t stream) {
    const float* nf  = (const float*)d_in[0];
    const float* adj = (const float*)d_in[1];
    const float* pm  = (const float*)d_in[2];
    const float* W1  = (const float*)d_in[3];
    const float* as1 = (const float*)d_in[4];
    const float* ad1 = (const float*)d_in[5];
    const float* g1  = (const float*)d_in[6];
    const float* b1  = (const float*)d_in[7];
    const float* W2  = (const float*)d_in[8];
    const float* as2 = (const float*)d_in[9];
    const float* ad2 = (const float*)d_in[10];
    const float* g2  = (const float*)d_in[11];
    const float* b2  = (const float*)d_in[12];
    const float* Ws  = (const float*)d_in[13];
    const float* bs  = (const float*)d_in[14];
    const float* Wo  = (const float*)d_in[15];
    const float* bo  = (const float*)d_in[16];
    float* out = (float*)d_out;

    float* p = (float*)d_ws;
    float* h1  = p; p += (size_t)N * F1;
    float* s1  = p; p += (size_t)N * HEADS;
    float* d1  = p; p += (size_t)N * HEADS;
    float* x1  = p; p += (size_t)N * F1;
    float* h2  = p; p += (size_t)N * F1;
    float* s2  = p; p += (size_t)N * HEADS;
    float* d2  = p; p += (size_t)N * HEADS;
    float* x2  = p; p += (size_t)N * HID;
    int* cnt = (int*)p;
    int* idx = cnt + N;

    k_build<<<N / 4, 256, 0, stream>>>(adj, cnt, idx);
    k_gemm1<<<N / RPB, 256, 0, stream>>>(nf, W1, as1, ad1, h1, s1, d1);
    k_agg1<<<N, 256, 0, stream>>>(h1, s1, d1, cnt, idx, g1, b1, x1);
    k_gemm2<<<N / RPB, 256, 0, stream>>>(x1, W2, as2, ad2, h2, s2, d2);
    k_agg2<<<N, 256, 0, stream>>>(h2, s2, d2, cnt, idx, g2, b2, x2);
    k_poolscore<<<C, 256, 0, stream>>>(pm, x2, Ws, bs, Wo, bo, out);
}

// Round 9
// 192.079 us; speedup vs baseline: 2.4488x; 1.0434x over previous
//
#include <hip/hip_runtime.h>
#include <math.h>

#define N 4096
#define C 512
#define EMB 38
#define HEADS 4
#define HID 64
#define F1 256       // HEADS*HID
#define MAXN 128     // max neighbors per row (p=0.01 -> mean 41, >13 sigma headroom)
#define RPB 8        // rows per block in gemms

__device__ __forceinline__ float wr_sum(float v) {
#pragma unroll
    for (int o = 32; o > 0; o >>= 1) v += __shfl_xor(v, o);
    return v;
}
__device__ __forceinline__ float wr_max(float v) {
#pragma unroll
    for (int o = 32; o > 0; o >>= 1) v = fmaxf(v, __shfl_xor(v, o));
    return v;
}

// ---------------- build CSR: wave per row; FULL-ROW register load (16 loads in flight),
// ballot compaction from registers, LDS stage, coalesced global write ----------------
// R8 lesson: prefetch depth 1 -> one 1KB load in flight per wave -> scan stuck at ~2.2 TB/s.
// 16 float4 in registers = 16 KB MLP/wave; 16 waves/CU saturates HBM.
__global__ __launch_bounds__(256) void k_build(const float* __restrict__ adj,
                                               int* __restrict__ cnt, int* __restrict__ idx) {
    int wv = threadIdx.x >> 6, lane = threadIdx.x & 63;
    int i = blockIdx.x * 4 + wv;
    __shared__ int stage[4][MAXN];
    const float4* row = (const float4*)(adj + (size_t)i * N);
    float4 v[16];
#pragma unroll
    for (int it = 0; it < 16; ++it) v[it] = row[it * 64 + lane];   // all 16 issued before any use
    unsigned long long below = (1ull << lane) - 1;
    int base = 0;
#pragma unroll
    for (int it = 0; it < 16; ++it) {
        int col0 = 4 * (it * 64 + lane);
        float vals[4] = {v[it].x, v[it].y, v[it].z, v[it].w};
#pragma unroll
        for (int comp = 0; comp < 4; ++comp) {
            unsigned long long m = __ballot(vals[comp] > 0.f);
            if (vals[comp] > 0.f) {
                int p = base + __popcll(m & below);
                if (p < MAXN) stage[wv][p] = col0 + comp;   // LDS scatter: contiguous -> conflict-free
            }
            base += __popcll(m);
        }
    }
    int c = min(base, MAXN);
    __syncthreads();
    if (lane < c)      idx[i * MAXN + lane]      = stage[wv][lane];
    if (lane + 64 < c) idx[i * MAXN + lane + 64] = stage[wv][lane + 64];
    if (lane == 0) cnt[i] = c;
}

// ---------------- fused embed + GEMM1 [8 nodes/block: 38->256] + attention dots ----------------
__global__ __launch_bounds__(256) void k_gemm1(const float* __restrict__ nf, const float* __restrict__ W1,
                                               const float* __restrict__ asrc, const float* __restrict__ adst,
                                               float* __restrict__ h1, float* __restrict__ s1, float* __restrict__ d1) {
    int n0 = blockIdx.x * RPB, tid = threadIdx.x;
    __shared__ float fs[RPB][8];
    __shared__ float xs[RPB][40];          // EMB=38 padded to 40, tail zeroed
    if (tid < RPB * 8) fs[tid >> 3][tid & 7] = nf[(size_t)n0 * 8 + tid];
    if (tid < RPB * 2) xs[tid >> 1][38 + (tid & 1)] = 0.f;
    __syncthreads();
    {
        int r = tid & 7;
        int t = tid >> 3;               // 0..31
        const float* f = fs[r];
        for (int pass = 0; pass < 2; ++pass, t += 32) {
            if (t >= EMB) break;
            float val;
            if (t < 6) { int nt = min(max((int)f[0], 0), 5); val = (t == nt) ? 1.f : 0.f; }
            else if (t == 6) val = log1pf(f[1]);
            else if (t < 31) {
                int q = (t - 7) & 7, s = (t - 7) >> 3, m = q >> 1;
                float base = (s == 0) ? f[2] : (s == 1) ? f[3] : f[4] * 100.f;
                float div = expf((2.f * m) * (-logf(10000.f) / 8.f));
                float sc = base * div;
                val = (q & 1) ? cosf(sc) : sinf(sc);
            }
            else if (t < 36) { int role = min(max((int)f[5], 0), 4); val = (t - 31 == role) ? 1.f : 0.f; }
            else val = (t == 36) ? f[6] : f[7];
            xs[r][t] = val;
        }
    }
    __syncthreads();
    float acc[RPB];
#pragma unroll
    for (int r = 0; r < RPB; ++r) acc[r] = 0.f;
#pragma unroll
    for (int kk = 0; kk < 9; ++kk) {      // k = 0..35 via float4 LDS broadcast
        float w0 = W1[(4 * kk + 0) * F1 + tid];
        float w1 = W1[(4 * kk + 1) * F1 + tid];
        float w2 = W1[(4 * kk + 2) * F1 + tid];
        float w3 = W1[(4 * kk + 3) * F1 + tid];
#pragma unroll
        for (int r = 0; r < RPB; ++r) {
            float4 x = *(const float4*)&xs[r][4 * kk];
            acc[r] = fmaf(x.x, w0, fmaf(x.y, w1, fmaf(x.z, w2, fmaf(x.w, w3, acc[r]))));
        }
    }
#pragma unroll
    for (int k = 36; k < EMB; ++k) {      // tail
        float wvv = W1[k * F1 + tid];
#pragma unroll
        for (int r = 0; r < RPB; ++r) acc[r] = fmaf(xs[r][k], wvv, acc[r]);
    }
    int h = tid >> 6, lane = tid & 63;
    float av = asrc[tid], dv = adst[tid];
#pragma unroll
    for (int r = 0; r < RPB; ++r) {
        h1[(size_t)(n0 + r) * F1 + tid] = acc[r];
        float ss = wr_sum(acc[r] * av);
        float dd = wr_sum(acc[r] * dv);
        if (lane == 0) { s1[(n0 + r) * HEADS + h] = ss; d1[(n0 + r) * HEADS + h] = dd; }
    }
}

// ---------------- GEMM2 [N,256]@[256,256] + fused attention dots (float4 LDS) ----------------
__global__ __launch_bounds__(256) void k_gemm2(const float* __restrict__ x1, const float* __restrict__ W2,
                                               const float* __restrict__ asrc, const float* __restrict__ adst,
                                               float* __restrict__ h2, float* __restrict__ s2, float* __restrict__ d2) {
    int n0 = blockIdx.x * RPB, tid = threadIdx.x;
    __shared__ float4 xs4[RPB][F1 / 4];
    {
        int r = tid >> 5, kk = tid & 31;
        const float4* x1v = (const float4*)x1;
        xs4[r][kk]      = x1v[(size_t)(n0 + r) * 64 + kk];
        xs4[r][kk + 32] = x1v[(size_t)(n0 + r) * 64 + kk + 32];
    }
    __syncthreads();
    float acc[RPB];
#pragma unroll
    for (int r = 0; r < RPB; ++r) acc[r] = 0.f;
    for (int kk = 0; kk < F1 / 4; ++kk) {
        float w0 = W2[(4 * kk + 0) * F1 + tid];
        float w1 = W2[(4 * kk + 1) * F1 + tid];
        float w2 = W2[(4 * kk + 2) * F1 + tid];
        float w3 = W2[(4 * kk + 3) * F1 + tid];
#pragma unroll
        for (int r = 0; r < RPB; ++r) {
            float4 x = xs4[r][kk];
            acc[r] = fmaf(x.x, w0, fmaf(x.y, w1, fmaf(x.z, w2, fmaf(x.w, w3, acc[r]))));
        }
    }
    int h = tid >> 6, lane = tid & 63;
    float av = asrc[tid], dv = adst[tid];
#pragma unroll
    for (int r = 0; r < RPB; ++r) {
        h2[(size_t)(n0 + r) * F1 + tid] = acc[r];
        float ss = wr_sum(acc[r] * av);
        float dd = wr_sum(acc[r] * dv);
        if (lane == 0) { s2[(n0 + r) * HEADS + h] = ss; d2[(n0 + r) * HEADS + h] = dd; }
    }
}

// ---------------- GAT aggregation layer 1 (concat) + LN(256) + ELU: 4-deep wave-split gather ----------------
__global__ __launch_bounds__(256) void k_agg1(const float* __restrict__ h1, const float* __restrict__ s1,
                                              const float* __restrict__ d1, const int* __restrict__ cnt,
                                              const int* __restrict__ idx, const float* __restrict__ g,
                                              const float* __restrict__ b, float* __restrict__ xo) {
    int i = blockIdx.x, tid = threadIdx.x;
    int wv = tid >> 6, lane = tid & 63;
    __shared__ int nbrs[MAXN];
    __shared__ float wts[HEADS][MAXN + 1];
    __shared__ float lsum[HEADS];
    __shared__ float sacc[4][F1];
    __shared__ float red[HEADS];
    int c = cnt[i];
    if (tid < c) nbrs[tid] = idx[i * MAXN + tid];
    __syncthreads();
    if (tid < c) {
        float4 dd = ((const float4*)d1)[nbrs[tid]];
        float4 ss = ((const float4*)s1)[i];
        float e0 = ss.x + dd.x, e1 = ss.y + dd.y, e2 = ss.z + dd.z, e3 = ss.w + dd.w;
        wts[0][tid] = e0 > 0.f ? e0 : 0.2f * e0;
        wts[1][tid] = e1 > 0.f ? e1 : 0.2f * e1;
        wts[2][tid] = e2 > 0.f ? e2 : 0.2f * e2;
        wts[3][tid] = e3 > 0.f ? e3 : 0.2f * e3;
    }
    __syncthreads();
    {   // per-head softmax normalize: wave wv owns head wv
        float m = -INFINITY;
        for (int jj = lane; jj < c; jj += 64) m = fmaxf(m, wts[wv][jj]);
        m = wr_max(m);
        float l = 0.f;
        for (int jj = lane; jj < c; jj += 64) { float t = expf(wts[wv][jj] - m); wts[wv][jj] = t; l += t; }
        l = wr_sum(l);
        if (lane == 0) lsum[wv] = l;
    }
    __syncthreads();
    int hq = lane >> 4;
    const float4* hv = (const float4*)h1;
    float4 acc = {0.f, 0.f, 0.f, 0.f};
    int jj = wv;
    for (; jj + 12 < c; jj += 16) {   // 4 loads in flight
        int na = nbrs[jj], nb = nbrs[jj + 4], nc = nbrs[jj + 8], nd = nbrs[jj + 12];
        float wa = wts[hq][jj], wb = wts[hq][jj + 4], wc = wts[hq][jj + 8], wd = wts[hq][jj + 12];
        float4 va = hv[(size_t)na * 64 + lane];
        float4 vb = hv[(size_t)nb * 64 + lane];
        float4 vc = hv[(size_t)nc * 64 + lane];
        float4 vd = hv[(size_t)nd * 64 + lane];
        acc.x = fmaf(wa, va.x, acc.x); acc.y = fmaf(wa, va.y, acc.y);
        acc.z = fmaf(wa, va.z, acc.z); acc.w = fmaf(wa, va.w, acc.w);
        acc.x = fmaf(wb, vb.x, acc.x); acc.y = fmaf(wb, vb.y, acc.y);
        acc.z = fmaf(wb, vb.z, acc.z); acc.w = fmaf(wb, vb.w, acc.w);
        acc.x = fmaf(wc, vc.x, acc.x); acc.y = fmaf(wc, vc.y, acc.y);
        acc.z = fmaf(wc, vc.z, acc.z); acc.w = fmaf(wc, vc.w, acc.w);
        acc.x = fmaf(wd, vd.x, acc.x); acc.y = fmaf(wd, vd.y, acc.y);
        acc.z = fmaf(wd, vd.z, acc.z); acc.w = fmaf(wd, vd.w, acc.w);
    }
    for (; jj < c; jj += 4) {
        int na = nbrs[jj];
        float wa = wts[hq][jj];
        float4 va = hv[(size_t)na * 64 + lane];
        acc.x = fmaf(wa, va.x, acc.x); acc.y = fmaf(wa, va.y, acc.y);
        acc.z = fmaf(wa, va.z, acc.z); acc.w = fmaf(wa, va.w, acc.w);
    }
    ((float4*)&sacc[wv][0])[lane] = acc;
    __syncthreads();
    float tot = (sacc[0][tid] + sacc[1][tid] + sacc[2][tid] + sacc[3][tid]) / lsum[wv];
    float s = wr_sum(tot);
    if (lane == 0) red[wv] = s;
    __syncthreads();
    float mu = (red[0] + red[1] + red[2] + red[3]) * (1.f / F1);
    float dvv = tot - mu;
    float s2 = wr_sum(dvv * dvv);
    __syncthreads();
    if (lane == 0) red[wv] = s2;
    __syncthreads();
    float var = (red[0] + red[1] + red[2] + red[3]) * (1.f / F1);
    float y = dvv * rsqrtf(var + 1e-5f) * g[tid] + b[tid];
    xo[(size_t)i * F1 + tid] = y > 0.f ? y : expm1f(y);
}

// ---------------- GAT aggregation layer 2 (mean heads) + LN(64) + ELU: 4-deep wave-split gather ----------------
__global__ __launch_bounds__(256) void k_agg2(const float* __restrict__ h2, const float* __restrict__ s2,
                                              const float* __restrict__ d2, const int* __restrict__ cnt,
                                              const int* __restrict__ idx, const float* __restrict__ g,
                                              const float* __restrict__ b, float* __restrict__ xo) {
    int i = blockIdx.x, tid = threadIdx.x;
    int wv = tid >> 6, lane = tid & 63;
    __shared__ int nbrs[MAXN];
    __shared__ float wts[HEADS][MAXN + 1];
    __shared__ float lsum[HEADS];
    __shared__ float sacc[4][F1];
    int c = cnt[i];
    if (tid < c) nbrs[tid] = idx[i * MAXN + tid];
    __syncthreads();
    if (tid < c) {
        float4 dd = ((const float4*)d2)[nbrs[tid]];
        float4 ss = ((const float4*)s2)[i];
        float e0 = ss.x + dd.x, e1 = ss.y + dd.y, e2 = ss.z + dd.z, e3 = ss.w + dd.w;
        wts[0][tid] = e0 > 0.f ? e0 : 0.2f * e0;
        wts[1][tid] = e1 > 0.f ? e1 : 0.2f * e1;
        wts[2][tid] = e2 > 0.f ? e2 : 0.2f * e2;
        wts[3][tid] = e3 > 0.f ? e3 : 0.2f * e3;
    }
    __syncthreads();
    {
        float m = -INFINITY;
        for (int jj = lane; jj < c; jj += 64) m = fmaxf(m, wts[wv][jj]);
        m = wr_max(m);
        float l = 0.f;
        for (int jj = lane; jj < c; jj += 64) { float t = expf(wts[wv][jj] - m); wts[wv][jj] = t; l += t; }
        l = wr_sum(l);
        if (lane == 0) lsum[wv] = l;
    }
    __syncthreads();
    int hq = lane >> 4;
    const float4* hvv = (const float4*)h2;
    float4 acc = {0.f, 0.f, 0.f, 0.f};
    int jj = wv;
    for (; jj + 12 < c; jj += 16) {
        int na = nbrs[jj], nb = nbrs[jj + 4], nc = nbrs[jj + 8], nd = nbrs[jj + 12];
        float wa = wts[hq][jj], wb = wts[hq][jj + 4], wc = wts[hq][jj + 8], wd = wts[hq][jj + 12];
        float4 va = hvv[(size_t)na * 64 + lane];
        float4 vb = hvv[(size_t)nb * 64 + lane];
        float4 vc = hvv[(size_t)nc * 64 + lane];
        float4 vd = hvv[(size_t)nd * 64 + lane];
        acc.x = fmaf(wa, va.x, acc.x); acc.y = fmaf(wa, va.y, acc.y);
        acc.z = fmaf(wa, va.z, acc.z); acc.w = fmaf(wa, va.w, acc.w);
        acc.x = fmaf(wb, vb.x, acc.x); acc.y = fmaf(wb, vb.y, acc.y);
        acc.z = fmaf(wb, vb.z, acc.z); acc.w = fmaf(wb, vb.w, acc.w);
        acc.x = fmaf(wc, vc.x, acc.x); acc.y = fmaf(wc, vc.y, acc.y);
        acc.z = fmaf(wc, vc.z, acc.z); acc.w = fmaf(wc, vc.w, acc.w);
        acc.x = fmaf(wd, vd.x, acc.x); acc.y = fmaf(wd, vd.y, acc.y);
        acc.z = fmaf(wd, vd.z, acc.z); acc.w = fmaf(wd, vd.w, acc.w);
    }
    for (; jj < c; jj += 4) {
        int na = nbrs[jj];
        float wa = wts[hq][jj];
        float4 va = hvv[(size_t)na * 64 + lane];
        acc.x = fmaf(wa, va.x, acc.x); acc.y = fmaf(wa, va.y, acc.y);
        acc.z = fmaf(wa, va.z, acc.z); acc.w = fmaf(wa, va.w, acc.w);
    }
    ((float4*)&sacc[wv][0])[lane] = acc;
    __syncthreads();
    if (wv == 0) {
        float t0 = 0.f, t1 = 0.f, t2 = 0.f, t3 = 0.f;
#pragma unroll
        for (int w = 0; w < 4; ++w) {
            t0 += sacc[w][lane];
            t1 += sacc[w][lane + 64];
            t2 += sacc[w][lane + 128];
            t3 += sacc[w][lane + 192];
        }
        float mv = (t0 / lsum[0] + t1 / lsum[1] + t2 / lsum[2] + t3 / lsum[3]) * 0.25f;
        float mu = wr_sum(mv) * (1.f / HID);
        float dvv = mv - mu;
        float var = wr_sum(dvv * dvv) * (1.f / HID);
        float y = dvv * rsqrtf(var + 1e-5f) * g[lane] + b[lane];
        xo[i * HID + lane] = y > 0.f ? y : expm1f(y);
    }
}

// ---------------- fused clause pooling + scorer ----------------
__global__ __launch_bounds__(256) void k_poolscore(const float* __restrict__ pm, const float* __restrict__ x2,
                                                   const float* __restrict__ Ws, const float* __restrict__ bs,
                                                   const float* __restrict__ Wo, const float* __restrict__ bo,
                                                   float* __restrict__ out) {
    int c = blockIdx.x, tid = threadIdx.x;
    int w = tid >> 6, lane = tid & 63;
    __shared__ float sacc[4][HID];
    __shared__ float ce_s[HID];
    float acc = 0.f;
    const float4* pmv = (const float4*)(pm + (size_t)c * N);
#pragma unroll
    for (int it = 0; it < 4; ++it) {
        int vi = w * 256 + it * 64 + lane;   // float4 index into the pm row
        float4 p4 = pmv[vi];
        float pc[4] = {p4.x, p4.y, p4.z, p4.w};
#pragma unroll
        for (int comp = 0; comp < 4; ++comp) {
            unsigned long long msk = __ballot(pc[comp] != 0.f);
            while (msk) {
                int bpos = __ffsll(msk) - 1;
                msk &= msk - 1;
                float pj = __shfl(pc[comp], bpos);
                int j = (w * 256 + it * 64 + bpos) * 4 + comp;
                acc += pj * x2[(size_t)j * HID + lane];
            }
        }
    }
    sacc[w][lane] = acc;
    __syncthreads();
    if (w == 0) ce_s[lane] = sacc[0][lane] + sacc[1][lane] + sacc[2][lane] + sacc[3][lane];
    __syncthreads();
    if (w == 0) {
        float hd = bs[lane];
#pragma unroll 8
        for (int k = 0; k < HID; ++k) hd = fmaf(ce_s[k], Ws[k * HID + lane], hd);
        hd = fmaxf(hd, 0.f);
        float v = wr_sum(hd * Wo[lane]);
        if (lane == 0) out[c] = v + bo[0];
    }
}

extern "C" void kernel_launch(void* const* d_in, const int* in_sizes, int n_in,
                              void* d_out, int out_size, void* d_ws, size_t ws_size,
                              hipStream_t stream) {
    const float* nf  = (const float*)d_in[0];
    const float* adj = (const float*)d_in[1];
    const float* pm  = (const float*)d_in[2];
    const float* W1  = (const float*)d_in[3];
    const float* as1 = (const float*)d_in[4];
    const float* ad1 = (const float*)d_in[5];
    const float* g1  = (const float*)d_in[6];
    const float* b1  = (const float*)d_in[7];
    const float* W2  = (const float*)d_in[8];
    const float* as2 = (const float*)d_in[9];
    const float* ad2 = (const float*)d_in[10];
    const float* g2  = (const float*)d_in[11];
    const float* b2  = (const float*)d_in[12];
    const float* Ws  = (const float*)d_in[13];
    const float* bs  = (const float*)d_in[14];
    const float* Wo  = (const float*)d_in[15];
    const float* bo  = (const float*)d_in[16];
    float* out = (float*)d_out;

    float* p = (float*)d_ws;
    float* h1  = p; p += (size_t)N * F1;
    float* s1  = p; p += (size_t)N * HEADS;
    float* d1  = p; p += (size_t)N * HEADS;
    float* x1  = p; p += (size_t)N * F1;
    float* h2  = p; p += (size_t)N * F1;
    float* s2  = p; p += (size_t)N * HEADS;
    float* d2  = p; p += (size_t)N * HEADS;
    float* x2  = p; p += (size_t)N * HID;
    int* cnt = (int*)p;
    int* idx = cnt + N;

    k_build<<<N / 4, 256, 0, stream>>>(adj, cnt, idx);
    k_gemm1<<<N / RPB, 256, 0, stream>>>(nf, W1, as1, ad1, h1, s1, d1);
    k_agg1<<<N, 256, 0, stream>>>(h1, s1, d1, cnt, idx, g1, b1, x1);
    k_gemm2<<<N / RPB, 256, 0, stream>>>(x1, W2, as2, ad2, h2, s2, d2);
    k_agg2<<<N, 256, 0, stream>>>(h2, s2, d2, cnt, idx, g2, b2, x2);
    k_poolscore<<<C, 256, 0, stream>>>(pm, x2, Ws, bs, Wo, bo, out);
}